// Round 1
// baseline (1152.315 us; speedup 1.0000x reference)
//
#include <hip/hip_runtime.h>
#include <hip/hip_bf16.h>

#define N_NODES 50000
#define N_EDGES 600000
#define N_GRAPHS 64
#define HID 128
#define NLAYERS 4
#define IN_DIM 5
#define NCLS 5
#define EPS 1e-5f
#define SCAN_BLK ((N_NODES + 511) / 512)

// ---------------- CSR build ----------------

__global__ void k_count(const int* __restrict__ dst, int* __restrict__ cnt) {
    int i = blockIdx.x * blockDim.x + threadIdx.x;
    if (i < N_EDGES) atomicAdd(&cnt[dst[i]], 1);
}

__global__ void k_scan1(const int* __restrict__ cnt, int* __restrict__ rp, int* __restrict__ bsum) {
    __shared__ int s[512];
    int t = threadIdx.x;
    int i = blockIdx.x * 512 + t;
    int v = (i < N_NODES) ? cnt[i] : 0;
    s[t] = v;
    __syncthreads();
    for (int off = 1; off < 512; off <<= 1) {
        int x = (t >= off) ? s[t - off] : 0;
        __syncthreads();
        s[t] += x;
        __syncthreads();
    }
    if (i < N_NODES) rp[i + 1] = s[t];
    if (t == 511) bsum[blockIdx.x] = s[511];
}

__global__ void k_scan2(int* bsum) {
    if (threadIdx.x == 0) {
        int acc = 0;
        for (int b = 0; b < SCAN_BLK; b++) { int v = bsum[b]; bsum[b] = acc; acc += v; }
    }
}

__global__ void k_scan3(int* __restrict__ rp, const int* __restrict__ bsum) {
    int i = blockIdx.x * 512 + threadIdx.x;
    if (i < N_NODES) rp[i + 1] += bsum[blockIdx.x];
    if (i == 0) rp[0] = 0;
}

__global__ void k_fill(const int* __restrict__ src, const int* __restrict__ dst,
                       const int* __restrict__ rp, int* __restrict__ cursor, int* __restrict__ col) {
    int e = blockIdx.x * blockDim.x + threadIdx.x;
    if (e < N_EDGES) {
        int d = dst[e];
        int pos = atomicAdd(&cursor[d], 1);
        col[rp[d] + pos] = src[e];
    }
}

__global__ void k_dinv(const int* __restrict__ cnt, float* __restrict__ dinv) {
    int i = blockIdx.x * blockDim.x + threadIdx.x;
    if (i < N_NODES) dinv[i] = rsqrtf((float)(cnt[i] + 1));
}

__global__ void k_gcnt(const int* __restrict__ batch, int* __restrict__ pcnt) {
    int i = blockIdx.x * blockDim.x + threadIdx.x;
    if (i < N_NODES) atomicAdd(&pcnt[batch[i]], 1);
}

// ---------------- input projection: h = x @ Wp + bp ----------------

__global__ void k_proj(const float* __restrict__ x, const float* __restrict__ Wp,
                       const float* __restrict__ bp, float* __restrict__ h) {
    int idx = blockIdx.x * blockDim.x + threadIdx.x;
    if (idx >= N_NODES * HID) return;
    int f = idx & (HID - 1);
    int n = idx >> 7;
    float acc = bp[f];
#pragma unroll
    for (int k = 0; k < IN_DIM; k++) acc += x[n * IN_DIM + k] * Wp[k * HID + f];
    h[idx] = acc;
}

// ---------------- GEMM: Bm = A @ W  (A: N x 128, W: 128 x 128) ----------------
// Each block handles a fixed 64-feature half (blockIdx&1); W-half (32KB) + 64-node
// h tile (32KB) in LDS; thread computes 4 nodes x 4 features.

__global__ __launch_bounds__(256) void k_gemm(const float* __restrict__ A,
                                              const float* __restrict__ W,
                                              float* __restrict__ Bm) {
    __shared__ float Wl[HID * 64];
    __shared__ float Hl[64 * HID];
    int t = threadIdx.x;
    int half = blockIdx.x & 1;
    int f0 = half * 64;
    {
        const float4* Wg4 = (const float4*)W;
        float4* Wl4 = (float4*)Wl;
        for (int idx = t; idx < HID * 16; idx += 256) {
            int k = idx >> 4, c = idx & 15;
            Wl4[idx] = Wg4[k * 32 + (f0 >> 2) + c];
        }
    }
    int fg = t & 15;
    int ng = t >> 4;   // 0..15
    int fl = fg * 4;
    const int numTiles = (N_NODES + 63) / 64;
    int stride = gridDim.x >> 1;
    for (int tile = blockIdx.x >> 1; tile < numTiles; tile += stride) {
        int n0 = tile * 64;
        __syncthreads();
        {
            float4* Hl4 = (float4*)Hl;
            const float4* Ag4 = (const float4*)(A + (size_t)n0 * HID);
            int lim = min(64, N_NODES - n0) * 32;
            for (int idx = t; idx < 64 * 32; idx += 256)
                Hl4[idx] = (idx < lim) ? Ag4[idx] : make_float4(0.f, 0.f, 0.f, 0.f);
        }
        __syncthreads();
        float acc[4][4];
#pragma unroll
        for (int j = 0; j < 4; j++)
#pragma unroll
            for (int c = 0; c < 4; c++) acc[j][c] = 0.f;
        for (int k = 0; k < HID; k += 4) {
            float4 w0 = *(const float4*)&Wl[(k + 0) * 64 + fl];
            float4 w1 = *(const float4*)&Wl[(k + 1) * 64 + fl];
            float4 w2 = *(const float4*)&Wl[(k + 2) * 64 + fl];
            float4 w3 = *(const float4*)&Wl[(k + 3) * 64 + fl];
#pragma unroll
            for (int j = 0; j < 4; j++) {
                float4 hv = *(const float4*)&Hl[(ng * 4 + j) * HID + k];
                acc[j][0] += hv.x * w0.x + hv.y * w1.x + hv.z * w2.x + hv.w * w3.x;
                acc[j][1] += hv.x * w0.y + hv.y * w1.y + hv.z * w2.y + hv.w * w3.y;
                acc[j][2] += hv.x * w0.z + hv.y * w1.z + hv.z * w2.z + hv.w * w3.z;
                acc[j][3] += hv.x * w0.w + hv.y * w1.w + hv.z * w2.w + hv.w * w3.w;
            }
        }
#pragma unroll
        for (int j = 0; j < 4; j++) {
            int n = n0 + ng * 4 + j;
            if (n < N_NODES)
                *(float4*)&Bm[(size_t)n * HID + f0 + fl] =
                    make_float4(acc[j][0], acc[j][1], acc[j][2], acc[j][3]);
        }
    }
}

// ---------------- CSR gather aggregation ----------------
// agg[v] = dinv[v] * ( m[v]*dinv[v] + sum_u m[u]*dinv[u] ) + bg
// (self-loop norm = dinv[v]^2, edge norm = dinv[u]*dinv[v], dv factored out)

__global__ __launch_bounds__(128) void k_gather(const float* __restrict__ Bm,
                                                const int* __restrict__ rp,
                                                const int* __restrict__ col,
                                                const float* __restrict__ dinv,
                                                const float* __restrict__ bg,
                                                float* __restrict__ Aout) {
    int v = blockIdx.x;
    int f = threadIdx.x;
    int beg = rp[v], end = rp[v + 1];
    float dv = dinv[v];
    float acc = Bm[(size_t)v * HID + f] * dv;  // self loop (times dv again below)
    int e = beg;
    for (; e + 1 < end; e += 2) {
        int u0 = col[e];
        int u1 = col[e + 1];
        float w0 = dinv[u0];
        float w1 = dinv[u1];
        acc += Bm[(size_t)u0 * HID + f] * w0;
        acc += Bm[(size_t)u1 * HID + f] * w1;
    }
    if (e < end) {
        int u = col[e];
        acc += Bm[(size_t)u * HID + f] * dinv[u];
    }
    Aout[(size_t)v * HID + f] = acc * dv + bg[f];
}

// ---------------- BatchNorm reduce + apply ----------------

__global__ __launch_bounds__(128) void k_bnred(const float* __restrict__ A,
                                               float* __restrict__ bnsum, float* __restrict__ bnsq) {
    int f = threadIdx.x;
    float s = 0.f, s2 = 0.f;
    for (int n = blockIdx.x; n < N_NODES; n += gridDim.x) {
        float v = A[(size_t)n * HID + f];
        s += v;
        s2 += v * v;
    }
    atomicAdd(&bnsum[f], s);
    atomicAdd(&bnsq[f], s2);
}

__global__ void k_bnapply(float* __restrict__ A, const float* __restrict__ bnsum,
                          const float* __restrict__ bnsq, const float* __restrict__ gamma,
                          const float* __restrict__ beta, const int* __restrict__ batch,
                          float* __restrict__ pmean, float* __restrict__ pmax, int last) {
    int idx = blockIdx.x * blockDim.x + threadIdx.x;
    if (idx >= N_NODES * HID) return;
    int f = idx & (HID - 1);
    int n = idx >> 7;
    const float invN = 1.f / (float)N_NODES;
    float mu = bnsum[f] * invN;
    float var = bnsq[f] * invN - mu * mu;
    float v = (A[idx] - mu) * rsqrtf(var + EPS) * gamma[f] + beta[f];
    v = fmaxf(v, 0.f);
    A[idx] = v;
    if (last) {
        int g = batch[n];
        atomicAdd(&pmean[g * HID + f], v);
        atomicMax(reinterpret_cast<unsigned int*>(&pmax[g * HID + f]), __float_as_uint(v));
    }
}

// ---------------- MLP head, one block per graph ----------------

__global__ __launch_bounds__(128) void k_head(const float* __restrict__ pmean,
                                              const float* __restrict__ pmax,
                                              const int* __restrict__ pcnt,
                                              const float* __restrict__ W1, const float* __restrict__ b1,
                                              const float* __restrict__ W2, const float* __restrict__ b2,
                                              const float* __restrict__ W3, const float* __restrict__ b3,
                                              float* __restrict__ out) {
    __shared__ float pooled[2 * HID];
    __shared__ float h1[HID];
    __shared__ float h2[HID / 2];
    int g = blockIdx.x, t = threadIdx.x;
    float cnt = fmaxf((float)pcnt[g], 1.f);
    pooled[t] = pmean[g * HID + t] / cnt;
    pooled[HID + t] = pmax[g * HID + t];
    __syncthreads();
    float acc = b1[t];
    for (int k = 0; k < 2 * HID; k++) acc += pooled[k] * W1[k * HID + t];
    h1[t] = fmaxf(acc, 0.f);
    __syncthreads();
    if (t < HID / 2) {
        float a2 = b2[t];
        for (int k = 0; k < HID; k++) a2 += h1[k] * W2[k * (HID / 2) + t];
        h2[t] = fmaxf(a2, 0.f);
    }
    __syncthreads();
    if (t < NCLS) {
        float a3 = b3[t];
        for (int k = 0; k < HID / 2; k++) a3 += h2[k] * W3[k * NCLS + t];
        out[g * NCLS + t] = a3;
    }
}

extern "C" void kernel_launch(void* const* d_in, const int* in_sizes, int n_in,
                              void* d_out, int out_size, void* d_ws, size_t ws_size,
                              hipStream_t stream) {
    const float* x     = (const float*)d_in[0];
    const int*   ei    = (const int*)d_in[1];
    const int*   batch = (const int*)d_in[2];
    const float* Wp    = (const float*)d_in[3];
    const float* bp    = (const float*)d_in[4];
    const float* Wg    = (const float*)d_in[5];
    const float* bg    = (const float*)d_in[6];
    const float* gamma = (const float*)d_in[7];
    const float* beta  = (const float*)d_in[8];
    const float* W1    = (const float*)d_in[9];
    const float* b1    = (const float*)d_in[10];
    const float* W2    = (const float*)d_in[11];
    const float* b2    = (const float*)d_in[12];
    const float* W3    = (const float*)d_in[13];
    const float* b3    = (const float*)d_in[14];
    const int* src = ei;
    const int* dst = ei + N_EDGES;
    float* out = (float*)d_out;

    char* base = (char*)d_ws;
    size_t off = 0;
    auto alloc = [&](size_t bytes) -> void* {
        void* p = base + off;
        off += (bytes + 255) & ~(size_t)255;
        return p;
    };
    // zeroed region (one memset covers all of it)
    int*   counts = (int*)alloc((size_t)N_NODES * 4);
    int*   cursor = (int*)alloc((size_t)N_NODES * 4);
    float* bnsum  = (float*)alloc((size_t)NLAYERS * HID * 4);
    float* bnsq   = (float*)alloc((size_t)NLAYERS * HID * 4);
    float* pmean  = (float*)alloc((size_t)N_GRAPHS * HID * 4);
    float* pmax   = (float*)alloc((size_t)N_GRAPHS * HID * 4);
    int*   pcnt   = (int*)alloc((size_t)N_GRAPHS * 4);
    size_t zeroBytes = off;
    // non-zeroed scratch
    int*   rp   = (int*)alloc((size_t)(N_NODES + 1) * 4);
    int*   bsum = (int*)alloc(128 * 4);
    int*   col  = (int*)alloc((size_t)N_EDGES * 4);
    float* dinv = (float*)alloc((size_t)N_NODES * 4);
    float* A    = (float*)alloc((size_t)N_NODES * HID * 4);
    float* B    = (float*)alloc((size_t)N_NODES * HID * 4);
    (void)ws_size; (void)in_sizes; (void)n_in; (void)out_size;

    hipMemsetAsync(d_ws, 0, zeroBytes, stream);

    k_count<<<(N_EDGES + 255) / 256, 256, 0, stream>>>(dst, counts);
    k_scan1<<<SCAN_BLK, 512, 0, stream>>>(counts, rp, bsum);
    k_scan2<<<1, 64, 0, stream>>>(bsum);
    k_scan3<<<SCAN_BLK, 512, 0, stream>>>(rp, bsum);
    k_fill<<<(N_EDGES + 255) / 256, 256, 0, stream>>>(src, dst, rp, cursor, col);
    k_dinv<<<(N_NODES + 255) / 256, 256, 0, stream>>>(counts, dinv);
    k_gcnt<<<(N_NODES + 255) / 256, 256, 0, stream>>>(batch, pcnt);
    k_proj<<<(N_NODES * HID + 255) / 256, 256, 0, stream>>>(x, Wp, bp, A);

    for (int i = 0; i < NLAYERS; i++) {
        k_gemm<<<1024, 256, 0, stream>>>(A, Wg + (size_t)i * HID * HID, B);
        k_gather<<<N_NODES, 128, 0, stream>>>(B, rp, col, dinv, bg + i * HID, A);
        k_bnred<<<256, 128, 0, stream>>>(A, bnsum + i * HID, bnsq + i * HID);
        k_bnapply<<<(N_NODES * HID + 255) / 256, 256, 0, stream>>>(
            A, bnsum + i * HID, bnsq + i * HID, gamma + i * HID, beta + i * HID,
            batch, pmean, pmax, (i == NLAYERS - 1) ? 1 : 0);
    }
    k_head<<<N_GRAPHS, HID, 0, stream>>>(pmean, pmax, pcnt, W1, b1, W2, b2, W3, b3, out);
}

// Round 2
// 973.032 us; speedup vs baseline: 1.1843x; 1.1843x over previous
//
#include <hip/hip_runtime.h>
#include <hip/hip_bf16.h>

#define N_NODES 50000
#define N_EDGES 600000
#define N_GRAPHS 64
#define HID 128
#define NLAYERS 4
#define IN_DIM 5
#define NCLS 5
#define EPS 1e-5f
#define SCAN_BLK ((N_NODES + 511) / 512)
#define BN_BLOCKS 256

// ---------------- CSR build ----------------

__global__ void k_count(const int* __restrict__ dst, int* __restrict__ cnt) {
    int i = blockIdx.x * blockDim.x + threadIdx.x;
    if (i < N_EDGES) atomicAdd(&cnt[dst[i]], 1);
}

__global__ void k_scan1(const int* __restrict__ cnt, int* __restrict__ rp, int* __restrict__ bsum) {
    __shared__ int s[512];
    int t = threadIdx.x;
    int i = blockIdx.x * 512 + t;
    int v = (i < N_NODES) ? cnt[i] : 0;
    s[t] = v;
    __syncthreads();
    for (int off = 1; off < 512; off <<= 1) {
        int x = (t >= off) ? s[t - off] : 0;
        __syncthreads();
        s[t] += x;
        __syncthreads();
    }
    if (i < N_NODES) rp[i + 1] = s[t];
    if (t == 511) bsum[blockIdx.x] = s[511];
}

__global__ void k_scan2(int* bsum) {
    if (threadIdx.x == 0) {
        int acc = 0;
        for (int b = 0; b < SCAN_BLK; b++) { int v = bsum[b]; bsum[b] = acc; acc += v; }
    }
}

__global__ void k_scan3(int* __restrict__ rp, const int* __restrict__ bsum) {
    int i = blockIdx.x * 512 + threadIdx.x;
    if (i < N_NODES) rp[i + 1] += bsum[blockIdx.x];
    if (i == 0) rp[0] = 0;
}

__global__ void k_dinv(const int* __restrict__ cnt, float* __restrict__ dinv) {
    int i = blockIdx.x * blockDim.x + threadIdx.x;
    if (i < N_NODES) dinv[i] = rsqrtf((float)(cnt[i] + 1));
}

// fill packed (col, w=dinv[src]) pairs
__global__ void k_fill(const int* __restrict__ src, const int* __restrict__ dst,
                       const int* __restrict__ rp, int* __restrict__ cursor,
                       int2* __restrict__ cw, const float* __restrict__ dinv) {
    int e = blockIdx.x * blockDim.x + threadIdx.x;
    if (e < N_EDGES) {
        int d = dst[e];
        int pos = atomicAdd(&cursor[d], 1);
        int s = src[e];
        int2 p;
        p.x = s;
        p.y = __float_as_int(dinv[s]);
        cw[rp[d] + pos] = p;
    }
}

// graph start offsets via binary search over sorted batch
__global__ void k_gstart(const int* __restrict__ batch, int* __restrict__ gstart) {
    int t = threadIdx.x;
    if (t <= N_GRAPHS) {
        int lo = 0, hi = N_NODES;
        while (lo < hi) {
            int mid = (lo + hi) >> 1;
            if (batch[mid] < t) lo = mid + 1; else hi = mid;
        }
        gstart[t] = lo;
    }
}

// ---------------- input projection: h = x @ Wp + bp ----------------

__global__ void k_proj(const float* __restrict__ x, const float* __restrict__ Wp,
                       const float* __restrict__ bp, float* __restrict__ h) {
    int idx = blockIdx.x * blockDim.x + threadIdx.x;
    if (idx >= N_NODES * HID) return;
    int f = idx & (HID - 1);
    int n = idx >> 7;
    float acc = bp[f];
#pragma unroll
    for (int k = 0; k < IN_DIM; k++) acc += x[n * IN_DIM + k] * Wp[k * HID + f];
    h[idx] = acc;
}

// ---------------- GEMM: Bm = act(A) @ W ----------------
// act(a) = bnflag ? relu(a*scale[k]+shift[k]) : a  (BN+ReLU of the previous
// layer folded into the tile load). Each block owns a 64-feature half.

__global__ __launch_bounds__(256) void k_gemm(const float* __restrict__ A,
                                              const float* __restrict__ W,
                                              float* __restrict__ Bm,
                                              const float* __restrict__ scale,
                                              const float* __restrict__ shift,
                                              int bnflag) {
    __shared__ float Wl[HID * 64];
    __shared__ float Hl[64 * HID];
    int t = threadIdx.x;
    int half = blockIdx.x & 1;
    int f0 = half * 64;
    {
        const float4* Wg4 = (const float4*)W;
        float4* Wl4 = (float4*)Wl;
        for (int idx = t; idx < HID * 16; idx += 256) {
            int k = idx >> 4, c = idx & 15;
            Wl4[idx] = Wg4[k * 32 + (f0 >> 2) + c];
        }
    }
    int fg = t & 15;
    int ng = t >> 4;
    int fl = fg * 4;
    const int numTiles = (N_NODES + 63) / 64;
    int stride = gridDim.x >> 1;
    for (int tile = blockIdx.x >> 1; tile < numTiles; tile += stride) {
        int n0 = tile * 64;
        __syncthreads();
        {
            float4* Hl4 = (float4*)Hl;
            const float4* Ag4 = (const float4*)(A + (size_t)n0 * HID);
            int lim = min(64, N_NODES - n0) * 32;
            for (int idx = t; idx < 64 * 32; idx += 256) {
                float4 hv = (idx < lim) ? Ag4[idx] : make_float4(0.f, 0.f, 0.f, 0.f);
                if (bnflag) {
                    int kf = (idx & 31) * 4;
                    float4 sc = *(const float4*)&scale[kf];
                    float4 sh = *(const float4*)&shift[kf];
                    hv.x = fmaxf(hv.x * sc.x + sh.x, 0.f);
                    hv.y = fmaxf(hv.y * sc.y + sh.y, 0.f);
                    hv.z = fmaxf(hv.z * sc.z + sh.z, 0.f);
                    hv.w = fmaxf(hv.w * sc.w + sh.w, 0.f);
                }
                Hl4[idx] = hv;
            }
        }
        __syncthreads();
        float acc[4][4];
#pragma unroll
        for (int j = 0; j < 4; j++)
#pragma unroll
            for (int c = 0; c < 4; c++) acc[j][c] = 0.f;
        for (int k = 0; k < HID; k += 4) {
            float4 w0 = *(const float4*)&Wl[(k + 0) * 64 + fl];
            float4 w1 = *(const float4*)&Wl[(k + 1) * 64 + fl];
            float4 w2 = *(const float4*)&Wl[(k + 2) * 64 + fl];
            float4 w3 = *(const float4*)&Wl[(k + 3) * 64 + fl];
#pragma unroll
            for (int j = 0; j < 4; j++) {
                float4 hv = *(const float4*)&Hl[(ng * 4 + j) * HID + k];
                acc[j][0] += hv.x * w0.x + hv.y * w1.x + hv.z * w2.x + hv.w * w3.x;
                acc[j][1] += hv.x * w0.y + hv.y * w1.y + hv.z * w2.y + hv.w * w3.y;
                acc[j][2] += hv.x * w0.z + hv.y * w1.z + hv.z * w2.z + hv.w * w3.z;
                acc[j][3] += hv.x * w0.w + hv.y * w1.w + hv.z * w2.w + hv.w * w3.w;
            }
        }
#pragma unroll
        for (int j = 0; j < 4; j++) {
            int n = n0 + ng * 4 + j;
            if (n < N_NODES)
                *(float4*)&Bm[(size_t)n * HID + f0 + fl] =
                    make_float4(acc[j][0], acc[j][1], acc[j][2], acc[j][3]);
        }
    }
}

// ---------------- CSR gather aggregation ----------------
// 4 nodes per block, one wave per node; float2 per lane (full 512B row in one
// dwordx2). agg[v] = dv*( m[v]*dv + sum_u m[u]*dinv[u] ) + bg.

__global__ __launch_bounds__(256) void k_gather(const float* __restrict__ Bm,
                                                const int* __restrict__ rp,
                                                const int2* __restrict__ cw,
                                                const float* __restrict__ dinv,
                                                const float* __restrict__ bg,
                                                float* __restrict__ Aout) {
    int wave = threadIdx.x >> 6;
    int lane = threadIdx.x & 63;
    int v = blockIdx.x * 4 + wave;
    int beg = rp[v], end = rp[v + 1];
    float dv = dinv[v];
    const float2* Bm2 = (const float2*)Bm;
    float2 self = Bm2[(size_t)v * 64 + lane];
    float2 acc = make_float2(self.x * dv, self.y * dv);
    int e = beg;
    for (; e + 1 < end; e += 2) {
        int2 p0 = cw[e];
        int2 p1 = cw[e + 1];
        float2 m0 = Bm2[(size_t)p0.x * 64 + lane];
        float2 m1 = Bm2[(size_t)p1.x * 64 + lane];
        float w0 = __int_as_float(p0.y);
        float w1 = __int_as_float(p1.y);
        acc.x += m0.x * w0 + m1.x * w1;
        acc.y += m0.y * w0 + m1.y * w1;
    }
    if (e < end) {
        int2 p = cw[e];
        float2 m = Bm2[(size_t)p.x * 64 + lane];
        float w = __int_as_float(p.y);
        acc.x += m.x * w;
        acc.y += m.y * w;
    }
    int f = lane * 2;
    float2 o;
    o.x = acc.x * dv + bg[f];
    o.y = acc.y * dv + bg[f + 1];
    ((float2*)Aout)[(size_t)v * 64 + lane] = o;
}

// ---------------- BatchNorm stats (no atomics) ----------------

__global__ __launch_bounds__(128) void k_bnred(const float* __restrict__ A,
                                               float* __restrict__ psum, float* __restrict__ psq) {
    int f = threadIdx.x;
    int b = blockIdx.x;
    float s = 0.f, s2 = 0.f;
    for (int n = b; n < N_NODES; n += gridDim.x) {
        float v = A[(size_t)n * HID + f];
        s += v;
        s2 += v * v;
    }
    psum[b * HID + f] = s;
    psq[b * HID + f] = s2;
}

__global__ void k_bnfin(const float* __restrict__ psum, const float* __restrict__ psq,
                        const float* __restrict__ gamma, const float* __restrict__ beta,
                        float* __restrict__ scale, float* __restrict__ shift) {
    int f = threadIdx.x;
    float s = 0.f, s2 = 0.f;
    for (int b = 0; b < BN_BLOCKS; b++) {
        s += psum[b * HID + f];
        s2 += psq[b * HID + f];
    }
    const float invN = 1.f / (float)N_NODES;
    float mu = s * invN;
    float var = s2 * invN - mu * mu;
    float rs = rsqrtf(var + EPS) * gamma[f];
    scale[f] = rs;
    shift[f] = beta[f] - mu * rs;
}

// ---------------- segmented pooling (batch sorted -> contiguous ranges) ----------------

__global__ __launch_bounds__(64) void k_pool(const float* __restrict__ A,
                                             const float* __restrict__ scale,
                                             const float* __restrict__ shift,
                                             const int* __restrict__ gstart,
                                             float* __restrict__ pooled) {
    int g = blockIdx.x;
    int f = blockIdx.y * 64 + threadIdx.x;
    int beg = gstart[g], end = gstart[g + 1];
    float sc = scale[f], sh = shift[f];
    float s = 0.f, mx = 0.f;
    for (int n = beg; n < end; n++) {
        float v = fmaxf(A[(size_t)n * HID + f] * sc + sh, 0.f);
        s += v;
        mx = fmaxf(mx, v);
    }
    float cnt = fmaxf((float)(end - beg), 1.f);
    pooled[g * 256 + f] = s / cnt;
    pooled[g * 256 + 128 + f] = mx;
}

// ---------------- MLP head, one block per graph ----------------

__global__ __launch_bounds__(128) void k_head(const float* __restrict__ pooled,
                                              const float* __restrict__ W1, const float* __restrict__ b1,
                                              const float* __restrict__ W2, const float* __restrict__ b2,
                                              const float* __restrict__ W3, const float* __restrict__ b3,
                                              float* __restrict__ out) {
    __shared__ float pl[2 * HID];
    __shared__ float h1[HID];
    __shared__ float h2[HID / 2];
    int g = blockIdx.x, t = threadIdx.x;
    pl[t] = pooled[g * 256 + t];
    pl[HID + t] = pooled[g * 256 + HID + t];
    __syncthreads();
    float acc = b1[t];
    for (int k = 0; k < 2 * HID; k++) acc += pl[k] * W1[k * HID + t];
    h1[t] = fmaxf(acc, 0.f);
    __syncthreads();
    if (t < HID / 2) {
        float a2 = b2[t];
        for (int k = 0; k < HID; k++) a2 += h1[k] * W2[k * (HID / 2) + t];
        h2[t] = fmaxf(a2, 0.f);
    }
    __syncthreads();
    if (t < NCLS) {
        float a3 = b3[t];
        for (int k = 0; k < HID / 2; k++) a3 += h2[k] * W3[k * NCLS + t];
        out[g * NCLS + t] = a3;
    }
}

extern "C" void kernel_launch(void* const* d_in, const int* in_sizes, int n_in,
                              void* d_out, int out_size, void* d_ws, size_t ws_size,
                              hipStream_t stream) {
    const float* x     = (const float*)d_in[0];
    const int*   ei    = (const int*)d_in[1];
    const int*   batch = (const int*)d_in[2];
    const float* Wp    = (const float*)d_in[3];
    const float* bp    = (const float*)d_in[4];
    const float* Wg    = (const float*)d_in[5];
    const float* bg    = (const float*)d_in[6];
    const float* gamma = (const float*)d_in[7];
    const float* beta  = (const float*)d_in[8];
    const float* W1    = (const float*)d_in[9];
    const float* b1    = (const float*)d_in[10];
    const float* W2    = (const float*)d_in[11];
    const float* b2    = (const float*)d_in[12];
    const float* W3    = (const float*)d_in[13];
    const float* b3    = (const float*)d_in[14];
    const int* src = ei;
    const int* dst = ei + N_EDGES;
    float* out = (float*)d_out;

    char* base = (char*)d_ws;
    size_t off = 0;
    auto alloc = [&](size_t bytes) -> void* {
        void* p = base + off;
        off += (bytes + 255) & ~(size_t)255;
        return p;
    };
    // zeroed region
    int*   counts = (int*)alloc((size_t)N_NODES * 4);
    int*   cursor = (int*)alloc((size_t)N_NODES * 4);
    size_t zeroBytes = off;
    // non-zeroed scratch
    int*   rp     = (int*)alloc((size_t)(N_NODES + 1) * 4);
    int*   bsum   = (int*)alloc(128 * 4);
    int2*  cw     = (int2*)alloc((size_t)N_EDGES * 8);
    float* dinv   = (float*)alloc((size_t)N_NODES * 4);
    float* psum   = (float*)alloc((size_t)BN_BLOCKS * HID * 4);
    float* psq    = (float*)alloc((size_t)BN_BLOCKS * HID * 4);
    float* scaleA = (float*)alloc((size_t)NLAYERS * HID * 4);
    float* shiftA = (float*)alloc((size_t)NLAYERS * HID * 4);
    int*   gstart = (int*)alloc((size_t)(N_GRAPHS + 1) * 4);
    float* pooled = (float*)alloc((size_t)N_GRAPHS * 256 * 4);
    float* A      = (float*)alloc((size_t)N_NODES * HID * 4);
    float* B      = (float*)alloc((size_t)N_NODES * HID * 4);
    (void)ws_size; (void)in_sizes; (void)n_in; (void)out_size;

    hipMemsetAsync(d_ws, 0, zeroBytes, stream);

    k_count<<<(N_EDGES + 255) / 256, 256, 0, stream>>>(dst, counts);
    k_scan1<<<SCAN_BLK, 512, 0, stream>>>(counts, rp, bsum);
    k_scan2<<<1, 64, 0, stream>>>(bsum);
    k_scan3<<<SCAN_BLK, 512, 0, stream>>>(rp, bsum);
    k_dinv<<<(N_NODES + 255) / 256, 256, 0, stream>>>(counts, dinv);
    k_fill<<<(N_EDGES + 255) / 256, 256, 0, stream>>>(src, dst, rp, cursor, cw, dinv);
    k_gstart<<<1, 128, 0, stream>>>(batch, gstart);
    k_proj<<<(N_NODES * HID + 255) / 256, 256, 0, stream>>>(x, Wp, bp, A);

    for (int i = 0; i < NLAYERS; i++) {
        const float* sc = scaleA + (i - 1) * HID;
        const float* sh = shiftA + (i - 1) * HID;
        k_gemm<<<1024, 256, 0, stream>>>(A, Wg + (size_t)i * HID * HID, B,
                                         (i == 0) ? scaleA : sc, (i == 0) ? shiftA : sh,
                                         (i == 0) ? 0 : 1);
        k_gather<<<N_NODES / 4, 256, 0, stream>>>(B, rp, cw, dinv, bg + i * HID, A);
        k_bnred<<<BN_BLOCKS, 128, 0, stream>>>(A, psum, psq);
        k_bnfin<<<1, 128, 0, stream>>>(psum, psq, gamma + i * HID, beta + i * HID,
                                       scaleA + i * HID, shiftA + i * HID);
    }
    dim3 pg(N_GRAPHS, 2);
    k_pool<<<pg, 64, 0, stream>>>(A, scaleA + 3 * HID, shiftA + 3 * HID, gstart, pooled);
    k_head<<<N_GRAPHS, 128, 0, stream>>>(pooled, W1, b1, W2, b2, W3, b3, out);
}

// Round 3
// 668.469 us; speedup vs baseline: 1.7238x; 1.4556x over previous
//
#include <hip/hip_runtime.h>
#include <hip/hip_bf16.h>

#define N_NODES 50000
#define N_EDGES 600000
#define N_GRAPHS 64
#define HID 128
#define NLAYERS 4
#define IN_DIM 5
#define NCLS 5
#define EPS 1e-5f
#define SCAN_BLK ((N_NODES + 511) / 512)
#define BN_BLOCKS 512
#define POOL_CHUNKS 16

// ---------------- CSR build ----------------

__global__ void k_count(const int* __restrict__ dst, int* __restrict__ cnt) {
    int i = blockIdx.x * blockDim.x + threadIdx.x;
    if (i < N_EDGES) atomicAdd(&cnt[dst[i]], 1);
}

__global__ void k_scan1(const int* __restrict__ cnt, int* __restrict__ rp, int* __restrict__ bsum) {
    __shared__ int s[512];
    int t = threadIdx.x;
    int i = blockIdx.x * 512 + t;
    int v = (i < N_NODES) ? cnt[i] : 0;
    s[t] = v;
    __syncthreads();
    for (int off = 1; off < 512; off <<= 1) {
        int x = (t >= off) ? s[t - off] : 0;
        __syncthreads();
        s[t] += x;
        __syncthreads();
    }
    if (i < N_NODES) rp[i + 1] = s[t];
    if (t == 511) bsum[blockIdx.x] = s[511];
}

__global__ void k_scan2(int* bsum) {
    if (threadIdx.x == 0) {
        int acc = 0;
        for (int b = 0; b < SCAN_BLK; b++) { int v = bsum[b]; bsum[b] = acc; acc += v; }
    }
}

__global__ void k_scan3(int* __restrict__ rp, const int* __restrict__ bsum) {
    int i = blockIdx.x * 512 + threadIdx.x;
    if (i < N_NODES) rp[i + 1] += bsum[blockIdx.x];
    if (i == 0) rp[0] = 0;
}

__global__ void k_dinv(const int* __restrict__ cnt, float* __restrict__ dinv) {
    int i = blockIdx.x * blockDim.x + threadIdx.x;
    if (i < N_NODES) dinv[i] = rsqrtf((float)(cnt[i] + 1));
}

// fill packed (col, w=dinv[src]) pairs
__global__ void k_fill(const int* __restrict__ src, const int* __restrict__ dst,
                       const int* __restrict__ rp, int* __restrict__ cursor,
                       int2* __restrict__ cw, const float* __restrict__ dinv) {
    int e = blockIdx.x * blockDim.x + threadIdx.x;
    if (e < N_EDGES) {
        int d = dst[e];
        int pos = atomicAdd(&cursor[d], 1);
        int s = src[e];
        int2 p;
        p.x = s;
        p.y = __float_as_int(dinv[s]);
        cw[rp[d] + pos] = p;
    }
}

// graph start offsets via binary search over sorted batch
__global__ void k_gstart(const int* __restrict__ batch, int* __restrict__ gstart) {
    int t = threadIdx.x;
    if (t <= N_GRAPHS) {
        int lo = 0, hi = N_NODES;
        while (lo < hi) {
            int mid = (lo + hi) >> 1;
            if (batch[mid] < t) lo = mid + 1; else hi = mid;
        }
        gstart[t] = lo;
    }
}

// ---------------- input projection: h = x @ Wp + bp ----------------

__global__ void k_proj(const float* __restrict__ x, const float* __restrict__ Wp,
                       const float* __restrict__ bp, float* __restrict__ h) {
    int idx = blockIdx.x * blockDim.x + threadIdx.x;
    if (idx >= N_NODES * HID) return;
    int f = idx & (HID - 1);
    int n = idx >> 7;
    float acc = bp[f];
#pragma unroll
    for (int k = 0; k < IN_DIM; k++) acc += x[n * IN_DIM + k] * Wp[k * HID + f];
    h[idx] = acc;
}

// ---------------- GEMM: Bm = act(A) @ W ----------------

__global__ __launch_bounds__(256) void k_gemm(const float* __restrict__ A,
                                              const float* __restrict__ W,
                                              float* __restrict__ Bm,
                                              const float* __restrict__ scale,
                                              const float* __restrict__ shift,
                                              int bnflag) {
    __shared__ float Wl[HID * 64];
    __shared__ float Hl[64 * HID];
    int t = threadIdx.x;
    int half = blockIdx.x & 1;
    int f0 = half * 64;
    {
        const float4* Wg4 = (const float4*)W;
        float4* Wl4 = (float4*)Wl;
        for (int idx = t; idx < HID * 16; idx += 256) {
            int k = idx >> 4, c = idx & 15;
            Wl4[idx] = Wg4[k * 32 + (f0 >> 2) + c];
        }
    }
    int fg = t & 15;
    int ng = t >> 4;
    int fl = fg * 4;
    const int numTiles = (N_NODES + 63) / 64;
    int stride = gridDim.x >> 1;
    for (int tile = blockIdx.x >> 1; tile < numTiles; tile += stride) {
        int n0 = tile * 64;
        __syncthreads();
        {
            float4* Hl4 = (float4*)Hl;
            const float4* Ag4 = (const float4*)(A + (size_t)n0 * HID);
            int lim = min(64, N_NODES - n0) * 32;
            for (int idx = t; idx < 64 * 32; idx += 256) {
                float4 hv = (idx < lim) ? Ag4[idx] : make_float4(0.f, 0.f, 0.f, 0.f);
                if (bnflag) {
                    int kf = (idx & 31) * 4;
                    float4 sc = *(const float4*)&scale[kf];
                    float4 sh = *(const float4*)&shift[kf];
                    hv.x = fmaxf(hv.x * sc.x + sh.x, 0.f);
                    hv.y = fmaxf(hv.y * sc.y + sh.y, 0.f);
                    hv.z = fmaxf(hv.z * sc.z + sh.z, 0.f);
                    hv.w = fmaxf(hv.w * sc.w + sh.w, 0.f);
                }
                Hl4[idx] = hv;
            }
        }
        __syncthreads();
        float acc[4][4];
#pragma unroll
        for (int j = 0; j < 4; j++)
#pragma unroll
            for (int c = 0; c < 4; c++) acc[j][c] = 0.f;
        for (int k = 0; k < HID; k += 4) {
            float4 w0 = *(const float4*)&Wl[(k + 0) * 64 + fl];
            float4 w1 = *(const float4*)&Wl[(k + 1) * 64 + fl];
            float4 w2 = *(const float4*)&Wl[(k + 2) * 64 + fl];
            float4 w3 = *(const float4*)&Wl[(k + 3) * 64 + fl];
#pragma unroll
            for (int j = 0; j < 4; j++) {
                float4 hv = *(const float4*)&Hl[(ng * 4 + j) * HID + k];
                acc[j][0] += hv.x * w0.x + hv.y * w1.x + hv.z * w2.x + hv.w * w3.x;
                acc[j][1] += hv.x * w0.y + hv.y * w1.y + hv.z * w2.y + hv.w * w3.y;
                acc[j][2] += hv.x * w0.z + hv.y * w1.z + hv.z * w2.z + hv.w * w3.z;
                acc[j][3] += hv.x * w0.w + hv.y * w1.w + hv.z * w2.w + hv.w * w3.w;
            }
        }
#pragma unroll
        for (int j = 0; j < 4; j++) {
            int n = n0 + ng * 4 + j;
            if (n < N_NODES)
                *(float4*)&Bm[(size_t)n * HID + f0 + fl] =
                    make_float4(acc[j][0], acc[j][1], acc[j][2], acc[j][3]);
        }
    }
}

// ---------------- CSR gather aggregation ----------------

__global__ __launch_bounds__(256) void k_gather(const float* __restrict__ Bm,
                                                const int* __restrict__ rp,
                                                const int2* __restrict__ cw,
                                                const float* __restrict__ dinv,
                                                const float* __restrict__ bg,
                                                float* __restrict__ Aout) {
    int wave = threadIdx.x >> 6;
    int lane = threadIdx.x & 63;
    int v = blockIdx.x * 4 + wave;
    int beg = rp[v], end = rp[v + 1];
    float dv = dinv[v];
    const float2* Bm2 = (const float2*)Bm;
    float2 self = Bm2[(size_t)v * 64 + lane];
    float2 acc = make_float2(self.x * dv, self.y * dv);
    int e = beg;
    for (; e + 1 < end; e += 2) {
        int2 p0 = cw[e];
        int2 p1 = cw[e + 1];
        float2 m0 = Bm2[(size_t)p0.x * 64 + lane];
        float2 m1 = Bm2[(size_t)p1.x * 64 + lane];
        float w0 = __int_as_float(p0.y);
        float w1 = __int_as_float(p1.y);
        acc.x += m0.x * w0 + m1.x * w1;
        acc.y += m0.y * w0 + m1.y * w1;
    }
    if (e < end) {
        int2 p = cw[e];
        float2 m = Bm2[(size_t)p.x * 64 + lane];
        float w = __int_as_float(p.y);
        acc.x += m.x * w;
        acc.y += m.y * w;
    }
    int f = lane * 2;
    float2 o;
    o.x = acc.x * dv + bg[f];
    o.y = acc.y * dv + bg[f + 1];
    ((float2*)Aout)[(size_t)v * 64 + lane] = o;
}

// ---------------- BatchNorm stats (wide, no atomics) ----------------
// 512 blocks x 512 threads; 4 row-streams per block, LDS reduce, one partial
// row per block.

__global__ __launch_bounds__(512) void k_bnred(const float* __restrict__ A,
                                               float* __restrict__ psum, float* __restrict__ psq) {
    __shared__ float ls[512], lq[512];
    int f = threadIdx.x & 127;
    int r = threadIdx.x >> 7;  // 0..3
    const int chunk = (N_NODES + BN_BLOCKS - 1) / BN_BLOCKS;
    int n0 = blockIdx.x * chunk;
    int n1 = min(n0 + chunk, N_NODES);
    float s = 0.f, s2 = 0.f;
    for (int n = n0 + r; n < n1; n += 4) {
        float v = A[(size_t)n * HID + f];
        s += v;
        s2 += v * v;
    }
    ls[threadIdx.x] = s;
    lq[threadIdx.x] = s2;
    __syncthreads();
    if (threadIdx.x < 128) {
        s = ls[f] + ls[128 + f] + ls[256 + f] + ls[384 + f];
        s2 = lq[f] + lq[128 + f] + lq[256 + f] + lq[384 + f];
        psum[blockIdx.x * HID + f] = s;
        psq[blockIdx.x * HID + f] = s2;
    }
}

__global__ __launch_bounds__(1024) void k_bnfin(const float* __restrict__ psum,
                                                const float* __restrict__ psq,
                                                const float* __restrict__ gamma,
                                                const float* __restrict__ beta,
                                                float* __restrict__ scale,
                                                float* __restrict__ shift) {
    __shared__ float ls[1024], lq[1024];
    int f = threadIdx.x & 127;
    int sl = threadIdx.x >> 7;  // 0..7
    float s = 0.f, s2 = 0.f;
    for (int b = sl; b < BN_BLOCKS; b += 8) {
        s += psum[b * HID + f];
        s2 += psq[b * HID + f];
    }
    ls[threadIdx.x] = s;
    lq[threadIdx.x] = s2;
    __syncthreads();
    if (threadIdx.x < 128) {
        s = 0.f; s2 = 0.f;
#pragma unroll
        for (int k = 0; k < 8; k++) {
            s += ls[k * 128 + f];
            s2 += lq[k * 128 + f];
        }
        const float invN = 1.f / (float)N_NODES;
        float mu = s * invN;
        float var = s2 * invN - mu * mu;
        float rs = rsqrtf(var + EPS) * gamma[f];
        scale[f] = rs;
        shift[f] = beta[f] - mu * rs;
    }
}

// ---------------- segmented pooling, chunked (batch sorted) ----------------

__global__ __launch_bounds__(128) void k_pool(const float* __restrict__ A,
                                              const float* __restrict__ scale,
                                              const float* __restrict__ shift,
                                              const int* __restrict__ gstart,
                                              float* __restrict__ poolPart) {
    int g = blockIdx.x;
    int c = blockIdx.y;
    int f = threadIdx.x;
    int beg = gstart[g], end = gstart[g + 1];
    int len = end - beg;
    int per = (len + POOL_CHUNKS - 1) / POOL_CHUNKS;
    int s0 = beg + c * per;
    int s1 = min(s0 + per, end);
    float sc = scale[f], sh = shift[f];
    float sa = 0.f, sb = 0.f, ma = 0.f, mb = 0.f;
    int n = s0;
    for (; n + 1 < s1; n += 2) {
        float v0 = A[(size_t)n * HID + f];
        float v1 = A[(size_t)(n + 1) * HID + f];
        v0 = fmaxf(v0 * sc + sh, 0.f);
        v1 = fmaxf(v1 * sc + sh, 0.f);
        sa += v0; ma = fmaxf(ma, v0);
        sb += v1; mb = fmaxf(mb, v1);
    }
    if (n < s1) {
        float v = fmaxf(A[(size_t)n * HID + f] * sc + sh, 0.f);
        sa += v; ma = fmaxf(ma, v);
    }
    poolPart[((size_t)g * POOL_CHUNKS + c) * 256 + f] = sa + sb;
    poolPart[((size_t)g * POOL_CHUNKS + c) * 256 + 128 + f] = fmaxf(ma, mb);
}

// ---------------- MLP head (reduces pool partials first) ----------------

__global__ __launch_bounds__(128) void k_head(const float* __restrict__ poolPart,
                                              const int* __restrict__ gstart,
                                              const float* __restrict__ W1, const float* __restrict__ b1,
                                              const float* __restrict__ W2, const float* __restrict__ b2,
                                              const float* __restrict__ W3, const float* __restrict__ b3,
                                              float* __restrict__ out) {
    __shared__ float pl[2 * HID];
    __shared__ float h1[HID];
    __shared__ float h2[HID / 2];
    int g = blockIdx.x, t = threadIdx.x;
    float cnt = fmaxf((float)(gstart[g + 1] - gstart[g]), 1.f);
    float s = 0.f, mx = 0.f;
#pragma unroll
    for (int c = 0; c < POOL_CHUNKS; c++) {
        const float* p = &poolPart[((size_t)g * POOL_CHUNKS + c) * 256];
        s += p[t];
        mx = fmaxf(mx, p[128 + t]);
    }
    pl[t] = s / cnt;
    pl[HID + t] = mx;
    __syncthreads();
    float acc = b1[t];
    for (int k = 0; k < 2 * HID; k++) acc += pl[k] * W1[k * HID + t];
    h1[t] = fmaxf(acc, 0.f);
    __syncthreads();
    if (t < HID / 2) {
        float a2 = b2[t];
        for (int k = 0; k < HID; k++) a2 += h1[k] * W2[k * (HID / 2) + t];
        h2[t] = fmaxf(a2, 0.f);
    }
    __syncthreads();
    if (t < NCLS) {
        float a3 = b3[t];
        for (int k = 0; k < HID / 2; k++) a3 += h2[k] * W3[k * NCLS + t];
        out[g * NCLS + t] = a3;
    }
}

extern "C" void kernel_launch(void* const* d_in, const int* in_sizes, int n_in,
                              void* d_out, int out_size, void* d_ws, size_t ws_size,
                              hipStream_t stream) {
    const float* x     = (const float*)d_in[0];
    const int*   ei    = (const int*)d_in[1];
    const int*   batch = (const int*)d_in[2];
    const float* Wp    = (const float*)d_in[3];
    const float* bp    = (const float*)d_in[4];
    const float* Wg    = (const float*)d_in[5];
    const float* bg    = (const float*)d_in[6];
    const float* gamma = (const float*)d_in[7];
    const float* beta  = (const float*)d_in[8];
    const float* W1    = (const float*)d_in[9];
    const float* b1    = (const float*)d_in[10];
    const float* W2    = (const float*)d_in[11];
    const float* b2    = (const float*)d_in[12];
    const float* W3    = (const float*)d_in[13];
    const float* b3    = (const float*)d_in[14];
    const int* src = ei;
    const int* dst = ei + N_EDGES;
    float* out = (float*)d_out;

    char* base = (char*)d_ws;
    size_t off = 0;
    auto alloc = [&](size_t bytes) -> void* {
        void* p = base + off;
        off += (bytes + 255) & ~(size_t)255;
        return p;
    };
    // zeroed region
    int*   counts = (int*)alloc((size_t)N_NODES * 4);
    int*   cursor = (int*)alloc((size_t)N_NODES * 4);
    size_t zeroBytes = off;
    // non-zeroed scratch
    int*   rp      = (int*)alloc((size_t)(N_NODES + 1) * 4);
    int*   bsum    = (int*)alloc(128 * 4);
    int2*  cw      = (int2*)alloc((size_t)N_EDGES * 8);
    float* dinv    = (float*)alloc((size_t)N_NODES * 4);
    float* psum    = (float*)alloc((size_t)BN_BLOCKS * HID * 4);
    float* psq     = (float*)alloc((size_t)BN_BLOCKS * HID * 4);
    float* scaleA  = (float*)alloc((size_t)NLAYERS * HID * 4);
    float* shiftA  = (float*)alloc((size_t)NLAYERS * HID * 4);
    int*   gstart  = (int*)alloc((size_t)(N_GRAPHS + 1) * 4);
    float* poolPart= (float*)alloc((size_t)N_GRAPHS * POOL_CHUNKS * 256 * 4);
    float* A       = (float*)alloc((size_t)N_NODES * HID * 4);
    float* B       = (float*)alloc((size_t)N_NODES * HID * 4);
    (void)ws_size; (void)in_sizes; (void)n_in; (void)out_size;

    hipMemsetAsync(d_ws, 0, zeroBytes, stream);

    k_count<<<(N_EDGES + 255) / 256, 256, 0, stream>>>(dst, counts);
    k_scan1<<<SCAN_BLK, 512, 0, stream>>>(counts, rp, bsum);
    k_scan2<<<1, 64, 0, stream>>>(bsum);
    k_scan3<<<SCAN_BLK, 512, 0, stream>>>(rp, bsum);
    k_dinv<<<(N_NODES + 255) / 256, 256, 0, stream>>>(counts, dinv);
    k_fill<<<(N_EDGES + 255) / 256, 256, 0, stream>>>(src, dst, rp, cursor, cw, dinv);
    k_gstart<<<1, 128, 0, stream>>>(batch, gstart);
    k_proj<<<(N_NODES * HID + 255) / 256, 256, 0, stream>>>(x, Wp, bp, A);

    for (int i = 0; i < NLAYERS; i++) {
        const float* sc = scaleA + (i - 1) * HID;
        const float* sh = shiftA + (i - 1) * HID;
        k_gemm<<<1024, 256, 0, stream>>>(A, Wg + (size_t)i * HID * HID, B,
                                         (i == 0) ? scaleA : sc, (i == 0) ? shiftA : sh,
                                         (i == 0) ? 0 : 1);
        k_gather<<<N_NODES / 4, 256, 0, stream>>>(B, rp, cw, dinv, bg + i * HID, A);
        k_bnred<<<BN_BLOCKS, 512, 0, stream>>>(A, psum, psq);
        k_bnfin<<<1, 1024, 0, stream>>>(psum, psq, gamma + i * HID, beta + i * HID,
                                        scaleA + i * HID, shiftA + i * HID);
    }
    dim3 pg(N_GRAPHS, POOL_CHUNKS);
    k_pool<<<pg, 128, 0, stream>>>(A, scaleA + 3 * HID, shiftA + 3 * HID, gstart, poolPart);
    k_head<<<N_GRAPHS, 128, 0, stream>>>(poolPart, gstart, W1, b1, W2, b2, W3, b3, out);
}

// Round 4
// 626.398 us; speedup vs baseline: 1.8396x; 1.0672x over previous
//
#include <hip/hip_runtime.h>
#include <hip/hip_bf16.h>

#define N_NODES 50000
#define N_EDGES 600000
#define N_GRAPHS 64
#define HID 128
#define NLAYERS 4
#define IN_DIM 5
#define NCLS 5
#define EPS 1e-5f
#define SCAN_BLK ((N_NODES + 511) / 512)
#define BN_BLOCKS 512
#define POOL_CHUNKS 16

// bf16 helpers (RNE)
__device__ __forceinline__ unsigned short f2bf(float x) {
    unsigned u = __float_as_uint(x);
    unsigned r = (u + 0x7fffu + ((u >> 16) & 1u)) >> 16;
    return (unsigned short)r;
}
__device__ __forceinline__ float2 bfpair(unsigned u) {
    float2 r;
    r.x = __uint_as_float(u << 16);
    r.y = __uint_as_float(u & 0xffff0000u);
    return r;
}

// ---------------- CSR build ----------------

__global__ void k_count(const int* __restrict__ dst, int* __restrict__ cnt) {
    int i = blockIdx.x * blockDim.x + threadIdx.x;
    if (i < N_EDGES) atomicAdd(&cnt[dst[i]], 1);
}

__global__ void k_scan1(const int* __restrict__ cnt, int* __restrict__ rp, int* __restrict__ bsum) {
    __shared__ int s[512];
    int t = threadIdx.x;
    int i = blockIdx.x * 512 + t;
    int v = (i < N_NODES) ? cnt[i] : 0;
    s[t] = v;
    __syncthreads();
    for (int off = 1; off < 512; off <<= 1) {
        int x = (t >= off) ? s[t - off] : 0;
        __syncthreads();
        s[t] += x;
        __syncthreads();
    }
    if (i < N_NODES) rp[i + 1] = s[t];
    if (t == 511) bsum[blockIdx.x] = s[511];
}

// parallel exclusive scan of the 98 block sums (was a 1-thread serial loop)
__global__ void k_scan2(int* __restrict__ bsum) {
    __shared__ int s[128];
    int t = threadIdx.x;
    int v = (t < SCAN_BLK) ? bsum[t] : 0;
    s[t] = v;
    __syncthreads();
    for (int off = 1; off < 128; off <<= 1) {
        int x = (t >= off) ? s[t - off] : 0;
        __syncthreads();
        s[t] += x;
        __syncthreads();
    }
    if (t < SCAN_BLK) bsum[t] = s[t] - v;  // exclusive
}

__global__ void k_scan3(int* __restrict__ rp, const int* __restrict__ bsum) {
    int i = blockIdx.x * 512 + threadIdx.x;
    if (i < N_NODES) rp[i + 1] += bsum[blockIdx.x];
    if (i == 0) rp[0] = 0;
}

__global__ void k_dinv(const int* __restrict__ cnt, float* __restrict__ dinv) {
    int i = blockIdx.x * blockDim.x + threadIdx.x;
    if (i < N_NODES) dinv[i] = rsqrtf((float)(cnt[i] + 1));
}

// fill packed (col, w=dinv[src]) pairs
__global__ void k_fill(const int* __restrict__ src, const int* __restrict__ dst,
                       const int* __restrict__ rp, int* __restrict__ cursor,
                       int2* __restrict__ cw, const float* __restrict__ dinv) {
    int e = blockIdx.x * blockDim.x + threadIdx.x;
    if (e < N_EDGES) {
        int d = dst[e];
        int pos = atomicAdd(&cursor[d], 1);
        int s = src[e];
        int2 p;
        p.x = s;
        p.y = __float_as_int(dinv[s]);
        cw[rp[d] + pos] = p;
    }
}

__global__ void k_gstart(const int* __restrict__ batch, int* __restrict__ gstart) {
    int t = threadIdx.x;
    if (t <= N_GRAPHS) {
        int lo = 0, hi = N_NODES;
        while (lo < hi) {
            int mid = (lo + hi) >> 1;
            if (batch[mid] < t) lo = mid + 1; else hi = mid;
        }
        gstart[t] = lo;
    }
}

// ---------------- input projection: h = x @ Wp + bp ----------------

__global__ void k_proj(const float* __restrict__ x, const float* __restrict__ Wp,
                       const float* __restrict__ bp, float* __restrict__ h) {
    int idx = blockIdx.x * blockDim.x + threadIdx.x;
    if (idx >= N_NODES * HID) return;
    int f = idx & (HID - 1);
    int n = idx >> 7;
    float acc = bp[f];
#pragma unroll
    for (int k = 0; k < IN_DIM; k++) acc += x[n * IN_DIM + k] * Wp[k * HID + f];
    h[idx] = acc;
}

// ---------------- GEMM: Bm(bf16) = act(A) @ W ----------------

__global__ __launch_bounds__(256) void k_gemm(const float* __restrict__ A,
                                              const float* __restrict__ W,
                                              unsigned short* __restrict__ Bm,
                                              const float* __restrict__ scale,
                                              const float* __restrict__ shift,
                                              int bnflag) {
    __shared__ float Wl[HID * 64];
    __shared__ float Hl[64 * HID];
    int t = threadIdx.x;
    int half = blockIdx.x & 1;
    int f0 = half * 64;
    {
        const float4* Wg4 = (const float4*)W;
        float4* Wl4 = (float4*)Wl;
        for (int idx = t; idx < HID * 16; idx += 256) {
            int k = idx >> 4, c = idx & 15;
            Wl4[idx] = Wg4[k * 32 + (f0 >> 2) + c];
        }
    }
    int fg = t & 15;
    int ng = t >> 4;
    int fl = fg * 4;
    const int numTiles = (N_NODES + 63) / 64;
    int stride = gridDim.x >> 1;
    for (int tile = blockIdx.x >> 1; tile < numTiles; tile += stride) {
        int n0 = tile * 64;
        __syncthreads();
        {
            float4* Hl4 = (float4*)Hl;
            const float4* Ag4 = (const float4*)(A + (size_t)n0 * HID);
            int lim = min(64, N_NODES - n0) * 32;
            for (int idx = t; idx < 64 * 32; idx += 256) {
                float4 hv = (idx < lim) ? Ag4[idx] : make_float4(0.f, 0.f, 0.f, 0.f);
                if (bnflag) {
                    int kf = (idx & 31) * 4;
                    float4 sc = *(const float4*)&scale[kf];
                    float4 sh = *(const float4*)&shift[kf];
                    hv.x = fmaxf(hv.x * sc.x + sh.x, 0.f);
                    hv.y = fmaxf(hv.y * sc.y + sh.y, 0.f);
                    hv.z = fmaxf(hv.z * sc.z + sh.z, 0.f);
                    hv.w = fmaxf(hv.w * sc.w + sh.w, 0.f);
                }
                Hl4[idx] = hv;
            }
        }
        __syncthreads();
        float acc[4][4];
#pragma unroll
        for (int j = 0; j < 4; j++)
#pragma unroll
            for (int c = 0; c < 4; c++) acc[j][c] = 0.f;
        for (int k = 0; k < HID; k += 4) {
            float4 w0 = *(const float4*)&Wl[(k + 0) * 64 + fl];
            float4 w1 = *(const float4*)&Wl[(k + 1) * 64 + fl];
            float4 w2 = *(const float4*)&Wl[(k + 2) * 64 + fl];
            float4 w3 = *(const float4*)&Wl[(k + 3) * 64 + fl];
#pragma unroll
            for (int j = 0; j < 4; j++) {
                float4 hv = *(const float4*)&Hl[(ng * 4 + j) * HID + k];
                acc[j][0] += hv.x * w0.x + hv.y * w1.x + hv.z * w2.x + hv.w * w3.x;
                acc[j][1] += hv.x * w0.y + hv.y * w1.y + hv.z * w2.y + hv.w * w3.y;
                acc[j][2] += hv.x * w0.z + hv.y * w1.z + hv.z * w2.z + hv.w * w3.z;
                acc[j][3] += hv.x * w0.w + hv.y * w1.w + hv.z * w2.w + hv.w * w3.w;
            }
        }
#pragma unroll
        for (int j = 0; j < 4; j++) {
            int n = n0 + ng * 4 + j;
            if (n < N_NODES) {
                ushort4 o;
                o.x = f2bf(acc[j][0]);
                o.y = f2bf(acc[j][1]);
                o.z = f2bf(acc[j][2]);
                o.w = f2bf(acc[j][3]);
                *(ushort4*)&Bm[(size_t)n * HID + f0 + fl] = o;
            }
        }
    }
}

// ---------------- CSR gather aggregation (bf16 rows, fp32 accumulate) ----------------

__global__ __launch_bounds__(256) void k_gather(const unsigned int* __restrict__ Bmu,
                                                const int* __restrict__ rp,
                                                const int2* __restrict__ cw,
                                                const float* __restrict__ dinv,
                                                const float* __restrict__ bg,
                                                float* __restrict__ Aout) {
    int wave = threadIdx.x >> 6;
    int lane = threadIdx.x & 63;
    int v = blockIdx.x * 4 + wave;
    int beg = rp[v], end = rp[v + 1];
    float dv = dinv[v];
    float2 self = bfpair(Bmu[(size_t)v * 64 + lane]);
    float2 acc = make_float2(self.x * dv, self.y * dv);
    int e = beg;
    for (; e + 1 < end; e += 2) {
        int2 p0 = cw[e];
        int2 p1 = cw[e + 1];
        unsigned u0 = Bmu[(size_t)p0.x * 64 + lane];
        unsigned u1 = Bmu[(size_t)p1.x * 64 + lane];
        float w0 = __int_as_float(p0.y);
        float w1 = __int_as_float(p1.y);
        float2 m0 = bfpair(u0);
        float2 m1 = bfpair(u1);
        acc.x += m0.x * w0 + m1.x * w1;
        acc.y += m0.y * w0 + m1.y * w1;
    }
    if (e < end) {
        int2 p = cw[e];
        float2 m = bfpair(Bmu[(size_t)p.x * 64 + lane]);
        float w = __int_as_float(p.y);
        acc.x += m.x * w;
        acc.y += m.y * w;
    }
    int f = lane * 2;
    float2 o;
    o.x = acc.x * dv + bg[f];
    o.y = acc.y * dv + bg[f + 1];
    ((float2*)Aout)[(size_t)v * 64 + lane] = o;
}

// ---------------- BatchNorm stats ----------------

__global__ __launch_bounds__(512) void k_bnred(const float* __restrict__ A,
                                               float* __restrict__ psum, float* __restrict__ psq) {
    __shared__ float ls[512], lq[512];
    int f = threadIdx.x & 127;
    int r = threadIdx.x >> 7;
    const int chunk = (N_NODES + BN_BLOCKS - 1) / BN_BLOCKS;
    int n0 = blockIdx.x * chunk;
    int n1 = min(n0 + chunk, N_NODES);
    float s = 0.f, s2 = 0.f;
    for (int n = n0 + r; n < n1; n += 4) {
        float v = A[(size_t)n * HID + f];
        s += v;
        s2 += v * v;
    }
    ls[threadIdx.x] = s;
    lq[threadIdx.x] = s2;
    __syncthreads();
    if (threadIdx.x < 128) {
        s = ls[f] + ls[128 + f] + ls[256 + f] + ls[384 + f];
        s2 = lq[f] + lq[128 + f] + lq[256 + f] + lq[384 + f];
        psum[blockIdx.x * HID + f] = s;
        psq[blockIdx.x * HID + f] = s2;
    }
}

__global__ __launch_bounds__(1024) void k_bnfin(const float* __restrict__ psum,
                                                const float* __restrict__ psq,
                                                const float* __restrict__ gamma,
                                                const float* __restrict__ beta,
                                                float* __restrict__ scale,
                                                float* __restrict__ shift) {
    __shared__ float ls[1024], lq[1024];
    int f = threadIdx.x & 127;
    int sl = threadIdx.x >> 7;
    float s = 0.f, s2 = 0.f;
    for (int b = sl; b < BN_BLOCKS; b += 8) {
        s += psum[b * HID + f];
        s2 += psq[b * HID + f];
    }
    ls[threadIdx.x] = s;
    lq[threadIdx.x] = s2;
    __syncthreads();
    if (threadIdx.x < 128) {
        s = 0.f; s2 = 0.f;
#pragma unroll
        for (int k = 0; k < 8; k++) {
            s += ls[k * 128 + f];
            s2 += lq[k * 128 + f];
        }
        const float invN = 1.f / (float)N_NODES;
        float mu = s * invN;
        float var = s2 * invN - mu * mu;
        float rs = rsqrtf(var + EPS) * gamma[f];
        scale[f] = rs;
        shift[f] = beta[f] - mu * rs;
    }
}

// ---------------- segmented pooling, chunked ----------------

__global__ __launch_bounds__(128) void k_pool(const float* __restrict__ A,
                                              const float* __restrict__ scale,
                                              const float* __restrict__ shift,
                                              const int* __restrict__ gstart,
                                              float* __restrict__ poolPart) {
    int g = blockIdx.x;
    int c = blockIdx.y;
    int f = threadIdx.x;
    int beg = gstart[g], end = gstart[g + 1];
    int len = end - beg;
    int per = (len + POOL_CHUNKS - 1) / POOL_CHUNKS;
    int s0 = beg + c * per;
    int s1 = min(s0 + per, end);
    float sc = scale[f], sh = shift[f];
    float sa = 0.f, sb = 0.f, ma = 0.f, mb = 0.f;
    int n = s0;
    for (; n + 1 < s1; n += 2) {
        float v0 = A[(size_t)n * HID + f];
        float v1 = A[(size_t)(n + 1) * HID + f];
        v0 = fmaxf(v0 * sc + sh, 0.f);
        v1 = fmaxf(v1 * sc + sh, 0.f);
        sa += v0; ma = fmaxf(ma, v0);
        sb += v1; mb = fmaxf(mb, v1);
    }
    if (n < s1) {
        float v = fmaxf(A[(size_t)n * HID + f] * sc + sh, 0.f);
        sa += v; ma = fmaxf(ma, v);
    }
    poolPart[((size_t)g * POOL_CHUNKS + c) * 256 + f] = sa + sb;
    poolPart[((size_t)g * POOL_CHUNKS + c) * 256 + 128 + f] = fmaxf(ma, mb);
}

// ---------------- MLP head ----------------

__global__ __launch_bounds__(128) void k_head(const float* __restrict__ poolPart,
                                              const int* __restrict__ gstart,
                                              const float* __restrict__ W1, const float* __restrict__ b1,
                                              const float* __restrict__ W2, const float* __restrict__ b2,
                                              const float* __restrict__ W3, const float* __restrict__ b3,
                                              float* __restrict__ out) {
    __shared__ float pl[2 * HID];
    __shared__ float h1[HID];
    __shared__ float h2[HID / 2];
    int g = blockIdx.x, t = threadIdx.x;
    float cnt = fmaxf((float)(gstart[g + 1] - gstart[g]), 1.f);
    float s = 0.f, mx = 0.f;
#pragma unroll
    for (int c = 0; c < POOL_CHUNKS; c++) {
        const float* p = &poolPart[((size_t)g * POOL_CHUNKS + c) * 256];
        s += p[t];
        mx = fmaxf(mx, p[128 + t]);
    }
    pl[t] = s / cnt;
    pl[HID + t] = mx;
    __syncthreads();
    float acc = b1[t];
    for (int k = 0; k < 2 * HID; k++) acc += pl[k] * W1[k * HID + t];
    h1[t] = fmaxf(acc, 0.f);
    __syncthreads();
    if (t < HID / 2) {
        float a2 = b2[t];
        for (int k = 0; k < HID; k++) a2 += h1[k] * W2[k * (HID / 2) + t];
        h2[t] = fmaxf(a2, 0.f);
    }
    __syncthreads();
    if (t < NCLS) {
        float a3 = b3[t];
        for (int k = 0; k < HID / 2; k++) a3 += h2[k] * W3[k * NCLS + t];
        out[g * NCLS + t] = a3;
    }
}

extern "C" void kernel_launch(void* const* d_in, const int* in_sizes, int n_in,
                              void* d_out, int out_size, void* d_ws, size_t ws_size,
                              hipStream_t stream) {
    const float* x     = (const float*)d_in[0];
    const int*   ei    = (const int*)d_in[1];
    const int*   batch = (const int*)d_in[2];
    const float* Wp    = (const float*)d_in[3];
    const float* bp    = (const float*)d_in[4];
    const float* Wg    = (const float*)d_in[5];
    const float* bg    = (const float*)d_in[6];
    const float* gamma = (const float*)d_in[7];
    const float* beta  = (const float*)d_in[8];
    const float* W1    = (const float*)d_in[9];
    const float* b1    = (const float*)d_in[10];
    const float* W2    = (const float*)d_in[11];
    const float* b2    = (const float*)d_in[12];
    const float* W3    = (const float*)d_in[13];
    const float* b3    = (const float*)d_in[14];
    const int* src = ei;
    const int* dst = ei + N_EDGES;
    float* out = (float*)d_out;

    char* base = (char*)d_ws;
    size_t off = 0;
    auto alloc = [&](size_t bytes) -> void* {
        void* p = base + off;
        off += (bytes + 255) & ~(size_t)255;
        return p;
    };
    // zeroed region
    int*   counts = (int*)alloc((size_t)N_NODES * 4);
    int*   cursor = (int*)alloc((size_t)N_NODES * 4);
    size_t zeroBytes = off;
    // non-zeroed scratch
    int*   rp      = (int*)alloc((size_t)(N_NODES + 1) * 4);
    int*   bsum    = (int*)alloc(128 * 4);
    int2*  cw      = (int2*)alloc((size_t)N_EDGES * 8);
    float* dinv    = (float*)alloc((size_t)N_NODES * 4);
    float* psum    = (float*)alloc((size_t)BN_BLOCKS * HID * 4);
    float* psq     = (float*)alloc((size_t)BN_BLOCKS * HID * 4);
    float* scaleA  = (float*)alloc((size_t)NLAYERS * HID * 4);
    float* shiftA  = (float*)alloc((size_t)NLAYERS * HID * 4);
    int*   gstart  = (int*)alloc((size_t)(N_GRAPHS + 1) * 4);
    float* poolPart= (float*)alloc((size_t)N_GRAPHS * POOL_CHUNKS * 256 * 4);
    float* A       = (float*)alloc((size_t)N_NODES * HID * 4);
    unsigned short* B = (unsigned short*)alloc((size_t)N_NODES * HID * 2);
    (void)ws_size; (void)in_sizes; (void)n_in; (void)out_size;

    hipMemsetAsync(d_ws, 0, zeroBytes, stream);

    k_count<<<(N_EDGES + 255) / 256, 256, 0, stream>>>(dst, counts);
    k_scan1<<<SCAN_BLK, 512, 0, stream>>>(counts, rp, bsum);
    k_scan2<<<1, 128, 0, stream>>>(bsum);
    k_scan3<<<SCAN_BLK, 512, 0, stream>>>(rp, bsum);
    k_dinv<<<(N_NODES + 255) / 256, 256, 0, stream>>>(counts, dinv);
    k_fill<<<(N_EDGES + 255) / 256, 256, 0, stream>>>(src, dst, rp, cursor, cw, dinv);
    k_gstart<<<1, 128, 0, stream>>>(batch, gstart);
    k_proj<<<(N_NODES * HID + 255) / 256, 256, 0, stream>>>(x, Wp, bp, A);

    for (int i = 0; i < NLAYERS; i++) {
        const float* sc = scaleA + (i - 1) * HID;
        const float* sh = shiftA + (i - 1) * HID;
        k_gemm<<<1024, 256, 0, stream>>>(A, Wg + (size_t)i * HID * HID, B,
                                         (i == 0) ? scaleA : sc, (i == 0) ? shiftA : sh,
                                         (i == 0) ? 0 : 1);
        k_gather<<<N_NODES / 4, 256, 0, stream>>>((const unsigned int*)B, rp, cw, dinv,
                                                  bg + i * HID, A);
        k_bnred<<<BN_BLOCKS, 512, 0, stream>>>(A, psum, psq);
        k_bnfin<<<1, 1024, 0, stream>>>(psum, psq, gamma + i * HID, beta + i * HID,
                                        scaleA + i * HID, shiftA + i * HID);
    }
    dim3 pg(N_GRAPHS, POOL_CHUNKS);
    k_pool<<<pg, 128, 0, stream>>>(A, scaleA + 3 * HID, shiftA + 3 * HID, gstart, poolPart);
    k_head<<<N_GRAPHS, 128, 0, stream>>>(poolPart, gstart, W1, b1, W2, b2, W3, b3, out);
}

// Round 5
// 564.386 us; speedup vs baseline: 2.0417x; 1.1099x over previous
//
#include <hip/hip_runtime.h>
#include <hip/hip_bf16.h>

#define N_NODES 50000
#define N_EDGES 600000
#define N_GRAPHS 64
#define HID 128
#define NLAYERS 4
#define IN_DIM 5
#define NCLS 5
#define EPS 1e-5f
#define SCAN_BLK ((N_NODES + 511) / 512)
#define BN_BLOCKS 512
#define POOL_CHUNKS 16
#define HLS 132  // Hl row stride: 132%32=4 -> consecutive rows hit different banks

// bf16 helpers (RNE)
__device__ __forceinline__ unsigned short f2bf(float x) {
    unsigned u = __float_as_uint(x);
    unsigned r = (u + 0x7fffu + ((u >> 16) & 1u)) >> 16;
    return (unsigned short)r;
}
__device__ __forceinline__ float2 bfpair(unsigned u) {
    float2 r;
    r.x = __uint_as_float(u << 16);
    r.y = __uint_as_float(u & 0xffff0000u);
    return r;
}
__device__ __forceinline__ float bf2f(unsigned short s) {
    return __uint_as_float(((unsigned)s) << 16);
}

// ---------------- CSR build ----------------

__global__ void k_count(const int* __restrict__ dst, int* __restrict__ cnt) {
    int i = blockIdx.x * blockDim.x + threadIdx.x;
    if (i < N_EDGES) atomicAdd(&cnt[dst[i]], 1);
}

__global__ void k_scan1(const int* __restrict__ cnt, int* __restrict__ rp, int* __restrict__ bsum) {
    __shared__ int s[512];
    int t = threadIdx.x;
    int i = blockIdx.x * 512 + t;
    int v = (i < N_NODES) ? cnt[i] : 0;
    s[t] = v;
    __syncthreads();
    for (int off = 1; off < 512; off <<= 1) {
        int x = (t >= off) ? s[t - off] : 0;
        __syncthreads();
        s[t] += x;
        __syncthreads();
    }
    if (i < N_NODES) rp[i + 1] = s[t];
    if (t == 511) bsum[blockIdx.x] = s[511];
}

// block 0: exclusive scan of block sums; block 1: gstart binary searches
__global__ void k_scan2g(int* __restrict__ bsum, const int* __restrict__ batch,
                         int* __restrict__ gstart) {
    if (blockIdx.x == 0) {
        __shared__ int s[128];
        int t = threadIdx.x;
        int v = (t < SCAN_BLK) ? bsum[t] : 0;
        s[t] = v;
        __syncthreads();
        for (int off = 1; off < 128; off <<= 1) {
            int x = (t >= off) ? s[t - off] : 0;
            __syncthreads();
            s[t] += x;
            __syncthreads();
        }
        if (t < SCAN_BLK) bsum[t] = s[t] - v;
    } else {
        int t = threadIdx.x;
        if (t <= N_GRAPHS) {
            int lo = 0, hi = N_NODES;
            while (lo < hi) {
                int mid = (lo + hi) >> 1;
                if (batch[mid] < t) lo = mid + 1; else hi = mid;
            }
            gstart[t] = lo;
        }
    }
}

// scan3 + dinv fused
__global__ void k_scan3d(int* __restrict__ rp, const int* __restrict__ bsum,
                         const int* __restrict__ cnt, float* __restrict__ dinv) {
    int i = blockIdx.x * 512 + threadIdx.x;
    if (i < N_NODES) {
        rp[i + 1] += bsum[blockIdx.x];
        dinv[i] = rsqrtf((float)(cnt[i] + 1));
    }
    if (i == 0) rp[0] = 0;
}

// fill packed (col, w=dinv[src]) pairs
__global__ void k_fill(const int* __restrict__ src, const int* __restrict__ dst,
                       const int* __restrict__ rp, int* __restrict__ cursor,
                       int2* __restrict__ cw, const float* __restrict__ dinv) {
    int e = blockIdx.x * blockDim.x + threadIdx.x;
    if (e < N_EDGES) {
        int d = dst[e];
        int pos = atomicAdd(&cursor[d], 1);
        int s = src[e];
        int2 p;
        p.x = s;
        p.y = __float_as_int(dinv[s]);
        cw[rp[d] + pos] = p;
    }
}

// ---------------- GEMM: Bm(bf16) = act(in) @ W ----------------
// layer 0: in = x @ Wp + bp computed per tile (proj fused); layers 1..3:
// in = relu(Abf*scale+shift) (BN+ReLU of prev layer folded into bf16 tile load).

__global__ __launch_bounds__(256) void k_gemm(const unsigned short* __restrict__ Abf,
                                              const float* __restrict__ x,
                                              const float* __restrict__ Wp,
                                              const float* __restrict__ bp,
                                              const float* __restrict__ W,
                                              unsigned short* __restrict__ Bm,
                                              const float* __restrict__ scale,
                                              const float* __restrict__ shift,
                                              int layer) {
    __shared__ float Wl[HID * 64];
    __shared__ float Hl[64 * HLS];
    __shared__ float xl[64 * IN_DIM];
    __shared__ float Wpl[IN_DIM * HID];
    __shared__ float bpl[HID];
    int t = threadIdx.x;
    int half = blockIdx.x & 1;
    int f0 = half * 64;
    {
        const float4* Wg4 = (const float4*)W;
        float4* Wl4 = (float4*)Wl;
        for (int idx = t; idx < HID * 16; idx += 256) {
            int k = idx >> 4, c = idx & 15;
            Wl4[idx] = Wg4[k * 32 + (f0 >> 2) + c];
        }
    }
    if (layer == 0) {
        for (int idx = t; idx < IN_DIM * HID; idx += 256) Wpl[idx] = Wp[idx];
        if (t < HID) bpl[t] = bp[t];
    }
    int fg = t & 15;
    int ng = t >> 4;
    int fl = fg * 4;
    const int numTiles = (N_NODES + 63) / 64;
    int stride = gridDim.x >> 1;
    for (int tile = blockIdx.x >> 1; tile < numTiles; tile += stride) {
        int n0 = tile * 64;
        __syncthreads();
        if (layer == 0) {
            for (int idx = t; idx < 64 * IN_DIM; idx += 256) {
                int g = n0 * IN_DIM + idx;
                xl[idx] = (g < N_NODES * IN_DIM) ? x[g] : 0.f;
            }
            __syncthreads();
            for (int idx = t; idx < 64 * HID; idx += 256) {
                int n = idx >> 7, k = idx & 127;
                float acc = bpl[k];
#pragma unroll
                for (int j = 0; j < IN_DIM; j++) acc += xl[n * IN_DIM + j] * Wpl[j * HID + k];
                Hl[n * HLS + k] = acc;
            }
        } else {
            const uint2* Ag = (const uint2*)(Abf + (size_t)n0 * HID);
            int limRow = min(64, N_NODES - n0);
            for (int idx = t; idx < 64 * 32; idx += 256) {
                int row = idx >> 5, c4 = idx & 31;
                uint2 u = (row < limRow) ? Ag[row * 32 + c4] : make_uint2(0u, 0u);
                float2 ab = bfpair(u.x);
                float2 cd = bfpair(u.y);
                int kf = c4 * 4;
                float4 sc = *(const float4*)&scale[kf];
                float4 sh = *(const float4*)&shift[kf];
                Hl[row * HLS + kf + 0] = fmaxf(ab.x * sc.x + sh.x, 0.f);
                Hl[row * HLS + kf + 1] = fmaxf(ab.y * sc.y + sh.y, 0.f);
                Hl[row * HLS + kf + 2] = fmaxf(cd.x * sc.z + sh.z, 0.f);
                Hl[row * HLS + kf + 3] = fmaxf(cd.y * sc.w + sh.w, 0.f);
            }
        }
        __syncthreads();
        float acc[4][4];
#pragma unroll
        for (int j = 0; j < 4; j++)
#pragma unroll
            for (int c = 0; c < 4; c++) acc[j][c] = 0.f;
        for (int k = 0; k < HID; k += 4) {
            float4 w0 = *(const float4*)&Wl[(k + 0) * 64 + fl];
            float4 w1 = *(const float4*)&Wl[(k + 1) * 64 + fl];
            float4 w2 = *(const float4*)&Wl[(k + 2) * 64 + fl];
            float4 w3 = *(const float4*)&Wl[(k + 3) * 64 + fl];
#pragma unroll
            for (int j = 0; j < 4; j++) {
                float4 hv = *(const float4*)&Hl[(ng * 4 + j) * HLS + k];
                acc[j][0] += hv.x * w0.x + hv.y * w1.x + hv.z * w2.x + hv.w * w3.x;
                acc[j][1] += hv.x * w0.y + hv.y * w1.y + hv.z * w2.y + hv.w * w3.y;
                acc[j][2] += hv.x * w0.z + hv.y * w1.z + hv.z * w2.z + hv.w * w3.z;
                acc[j][3] += hv.x * w0.w + hv.y * w1.w + hv.z * w2.w + hv.w * w3.w;
            }
        }
#pragma unroll
        for (int j = 0; j < 4; j++) {
            int n = n0 + ng * 4 + j;
            if (n < N_NODES) {
                ushort4 o;
                o.x = f2bf(acc[j][0]);
                o.y = f2bf(acc[j][1]);
                o.z = f2bf(acc[j][2]);
                o.w = f2bf(acc[j][3]);
                *(ushort4*)&Bm[(size_t)n * HID + f0 + fl] = o;
            }
        }
    }
}

// ---------------- CSR gather aggregation (bf16 rows, fp32 acc, unroll 4) ----------------

__global__ __launch_bounds__(256) void k_gather(const unsigned int* __restrict__ Bmu,
                                                const int* __restrict__ rp,
                                                const int2* __restrict__ cw,
                                                const float* __restrict__ dinv,
                                                const float* __restrict__ bg,
                                                unsigned short* __restrict__ Aout) {
    int wave = threadIdx.x >> 6;
    int lane = threadIdx.x & 63;
    int v = blockIdx.x * 4 + wave;
    int beg = rp[v], end = rp[v + 1];
    float dv = dinv[v];
    float2 self = bfpair(Bmu[(size_t)v * 64 + lane]);
    float2 acc = make_float2(self.x * dv, self.y * dv);
    int e = beg;
    for (; e + 3 < end; e += 4) {
        int2 p0 = cw[e];
        int2 p1 = cw[e + 1];
        int2 p2 = cw[e + 2];
        int2 p3 = cw[e + 3];
        unsigned u0 = Bmu[(size_t)p0.x * 64 + lane];
        unsigned u1 = Bmu[(size_t)p1.x * 64 + lane];
        unsigned u2 = Bmu[(size_t)p2.x * 64 + lane];
        unsigned u3 = Bmu[(size_t)p3.x * 64 + lane];
        float2 m0 = bfpair(u0);
        float2 m1 = bfpair(u1);
        float2 m2 = bfpair(u2);
        float2 m3 = bfpair(u3);
        float w0 = __int_as_float(p0.y), w1 = __int_as_float(p1.y);
        float w2 = __int_as_float(p2.y), w3 = __int_as_float(p3.y);
        acc.x += m0.x * w0 + m1.x * w1 + m2.x * w2 + m3.x * w3;
        acc.y += m0.y * w0 + m1.y * w1 + m2.y * w2 + m3.y * w3;
    }
    for (; e < end; e++) {
        int2 p = cw[e];
        float2 m = bfpair(Bmu[(size_t)p.x * 64 + lane]);
        float w = __int_as_float(p.y);
        acc.x += m.x * w;
        acc.y += m.y * w;
    }
    int f = lane * 2;
    ushort2 o;
    o.x = f2bf(acc.x * dv + bg[f]);
    o.y = f2bf(acc.y * dv + bg[f + 1]);
    ((ushort2*)Aout)[(size_t)v * 64 + lane] = o;
}

// ---------------- BatchNorm stats (bf16 input) ----------------

__global__ __launch_bounds__(512) void k_bnred(const unsigned short* __restrict__ A,
                                               float* __restrict__ psum, float* __restrict__ psq) {
    __shared__ float ls[512], lq[512];
    int f = threadIdx.x & 127;
    int r = threadIdx.x >> 7;
    const int chunk = (N_NODES + BN_BLOCKS - 1) / BN_BLOCKS;
    int n0 = blockIdx.x * chunk;
    int n1 = min(n0 + chunk, N_NODES);
    float s = 0.f, s2 = 0.f;
    for (int n = n0 + r; n < n1; n += 4) {
        float v = bf2f(A[(size_t)n * HID + f]);
        s += v;
        s2 += v * v;
    }
    ls[threadIdx.x] = s;
    lq[threadIdx.x] = s2;
    __syncthreads();
    if (threadIdx.x < 128) {
        s = ls[f] + ls[128 + f] + ls[256 + f] + ls[384 + f];
        s2 = lq[f] + lq[128 + f] + lq[256 + f] + lq[384 + f];
        psum[blockIdx.x * HID + f] = s;
        psq[blockIdx.x * HID + f] = s2;
    }
}

__global__ __launch_bounds__(1024) void k_bnfin(const float* __restrict__ psum,
                                                const float* __restrict__ psq,
                                                const float* __restrict__ gamma,
                                                const float* __restrict__ beta,
                                                float* __restrict__ scale,
                                                float* __restrict__ shift) {
    __shared__ float ls[1024], lq[1024];
    int f = threadIdx.x & 127;
    int sl = threadIdx.x >> 7;
    float s = 0.f, s2 = 0.f;
    for (int b = sl; b < BN_BLOCKS; b += 8) {
        s += psum[b * HID + f];
        s2 += psq[b * HID + f];
    }
    ls[threadIdx.x] = s;
    lq[threadIdx.x] = s2;
    __syncthreads();
    if (threadIdx.x < 128) {
        s = 0.f; s2 = 0.f;
#pragma unroll
        for (int k = 0; k < 8; k++) {
            s += ls[k * 128 + f];
            s2 += lq[k * 128 + f];
        }
        const float invN = 1.f / (float)N_NODES;
        float mu = s * invN;
        float var = s2 * invN - mu * mu;
        float rs = rsqrtf(var + EPS) * gamma[f];
        scale[f] = rs;
        shift[f] = beta[f] - mu * rs;
    }
}

// ---------------- segmented pooling, chunked (bf16 input) ----------------

__global__ __launch_bounds__(128) void k_pool(const unsigned short* __restrict__ A,
                                              const float* __restrict__ scale,
                                              const float* __restrict__ shift,
                                              const int* __restrict__ gstart,
                                              float* __restrict__ poolPart) {
    int g = blockIdx.x;
    int c = blockIdx.y;
    int f = threadIdx.x;
    int beg = gstart[g], end = gstart[g + 1];
    int len = end - beg;
    int per = (len + POOL_CHUNKS - 1) / POOL_CHUNKS;
    int s0 = beg + c * per;
    int s1 = min(s0 + per, end);
    float sc = scale[f], sh = shift[f];
    float sa = 0.f, sb = 0.f, ma = 0.f, mb = 0.f;
    int n = s0;
    for (; n + 1 < s1; n += 2) {
        float v0 = bf2f(A[(size_t)n * HID + f]);
        float v1 = bf2f(A[(size_t)(n + 1) * HID + f]);
        v0 = fmaxf(v0 * sc + sh, 0.f);
        v1 = fmaxf(v1 * sc + sh, 0.f);
        sa += v0; ma = fmaxf(ma, v0);
        sb += v1; mb = fmaxf(mb, v1);
    }
    if (n < s1) {
        float v = fmaxf(bf2f(A[(size_t)n * HID + f]) * sc + sh, 0.f);
        sa += v; ma = fmaxf(ma, v);
    }
    poolPart[((size_t)g * POOL_CHUNKS + c) * 256 + f] = sa + sb;
    poolPart[((size_t)g * POOL_CHUNKS + c) * 256 + 128 + f] = fmaxf(ma, mb);
}

// ---------------- MLP head ----------------

__global__ __launch_bounds__(128) void k_head(const float* __restrict__ poolPart,
                                              const int* __restrict__ gstart,
                                              const float* __restrict__ W1, const float* __restrict__ b1,
                                              const float* __restrict__ W2, const float* __restrict__ b2,
                                              const float* __restrict__ W3, const float* __restrict__ b3,
                                              float* __restrict__ out) {
    __shared__ float pl[2 * HID];
    __shared__ float h1[HID];
    __shared__ float h2[HID / 2];
    int g = blockIdx.x, t = threadIdx.x;
    float cnt = fmaxf((float)(gstart[g + 1] - gstart[g]), 1.f);
    float s = 0.f, mx = 0.f;
#pragma unroll
    for (int c = 0; c < POOL_CHUNKS; c++) {
        const float* p = &poolPart[((size_t)g * POOL_CHUNKS + c) * 256];
        s += p[t];
        mx = fmaxf(mx, p[128 + t]);
    }
    pl[t] = s / cnt;
    pl[HID + t] = mx;
    __syncthreads();
    float acc = b1[t];
    for (int k = 0; k < 2 * HID; k++) acc += pl[k] * W1[k * HID + t];
    h1[t] = fmaxf(acc, 0.f);
    __syncthreads();
    if (t < HID / 2) {
        float a2 = b2[t];
        for (int k = 0; k < HID; k++) a2 += h1[k] * W2[k * (HID / 2) + t];
        h2[t] = fmaxf(a2, 0.f);
    }
    __syncthreads();
    if (t < NCLS) {
        float a3 = b3[t];
        for (int k = 0; k < HID / 2; k++) a3 += h2[k] * W3[k * NCLS + t];
        out[g * NCLS + t] = a3;
    }
}

extern "C" void kernel_launch(void* const* d_in, const int* in_sizes, int n_in,
                              void* d_out, int out_size, void* d_ws, size_t ws_size,
                              hipStream_t stream) {
    const float* x     = (const float*)d_in[0];
    const int*   ei    = (const int*)d_in[1];
    const int*   batch = (const int*)d_in[2];
    const float* Wp    = (const float*)d_in[3];
    const float* bp    = (const float*)d_in[4];
    const float* Wg    = (const float*)d_in[5];
    const float* bg    = (const float*)d_in[6];
    const float* gamma = (const float*)d_in[7];
    const float* beta  = (const float*)d_in[8];
    const float* W1    = (const float*)d_in[9];
    const float* b1    = (const float*)d_in[10];
    const float* W2    = (const float*)d_in[11];
    const float* b2    = (const float*)d_in[12];
    const float* W3    = (const float*)d_in[13];
    const float* b3    = (const float*)d_in[14];
    const int* src = ei;
    const int* dst = ei + N_EDGES;
    float* out = (float*)d_out;

    char* base = (char*)d_ws;
    size_t off = 0;
    auto alloc = [&](size_t bytes) -> void* {
        void* p = base + off;
        off += (bytes + 255) & ~(size_t)255;
        return p;
    };
    // zeroed region
    int*   counts = (int*)alloc((size_t)N_NODES * 4);
    int*   cursor = (int*)alloc((size_t)N_NODES * 4);
    size_t zeroBytes = off;
    // non-zeroed scratch
    int*   rp      = (int*)alloc((size_t)(N_NODES + 1) * 4);
    int*   bsum    = (int*)alloc(128 * 4);
    int2*  cw      = (int2*)alloc((size_t)N_EDGES * 8);
    float* dinv    = (float*)alloc((size_t)N_NODES * 4);
    float* psum    = (float*)alloc((size_t)BN_BLOCKS * HID * 4);
    float* psq     = (float*)alloc((size_t)BN_BLOCKS * HID * 4);
    float* scaleA  = (float*)alloc((size_t)NLAYERS * HID * 4);
    float* shiftA  = (float*)alloc((size_t)NLAYERS * HID * 4);
    int*   gstart  = (int*)alloc((size_t)(N_GRAPHS + 1) * 4);
    float* poolPart= (float*)alloc((size_t)N_GRAPHS * POOL_CHUNKS * 256 * 4);
    unsigned short* A = (unsigned short*)alloc((size_t)N_NODES * HID * 2);
    unsigned short* B = (unsigned short*)alloc((size_t)N_NODES * HID * 2);
    (void)ws_size; (void)in_sizes; (void)n_in; (void)out_size;

    hipMemsetAsync(d_ws, 0, zeroBytes, stream);

    k_count<<<(N_EDGES + 255) / 256, 256, 0, stream>>>(dst, counts);
    k_scan1<<<SCAN_BLK, 512, 0, stream>>>(counts, rp, bsum);
    k_scan2g<<<2, 128, 0, stream>>>(bsum, batch, gstart);
    k_scan3d<<<SCAN_BLK, 512, 0, stream>>>(rp, bsum, counts, dinv);
    k_fill<<<(N_EDGES + 255) / 256, 256, 0, stream>>>(src, dst, rp, cursor, cw, dinv);

    for (int i = 0; i < NLAYERS; i++) {
        const float* sc = scaleA + (i - 1) * HID;
        const float* sh = shiftA + (i - 1) * HID;
        k_gemm<<<1024, 256, 0, stream>>>(A, x, Wp, bp, Wg + (size_t)i * HID * HID, B,
                                         (i == 0) ? scaleA : sc, (i == 0) ? shiftA : sh, i);
        k_gather<<<N_NODES / 4, 256, 0, stream>>>((const unsigned int*)B, rp, cw, dinv,
                                                  bg + i * HID, A);
        k_bnred<<<BN_BLOCKS, 512, 0, stream>>>(A, psum, psq);
        k_bnfin<<<1, 1024, 0, stream>>>(psum, psq, gamma + i * HID, beta + i * HID,
                                        scaleA + i * HID, shiftA + i * HID);
    }
    dim3 pg(N_GRAPHS, POOL_CHUNKS);
    k_pool<<<pg, 128, 0, stream>>>(A, scaleA + 3 * HID, shiftA + 3 * HID, gstart, poolPart);
    k_head<<<N_GRAPHS, 128, 0, stream>>>(poolPart, gstart, W1, b1, W2, b2, W3, b3, out);
}

// Round 6
// 450.204 us; speedup vs baseline: 2.5595x; 1.2536x over previous
//
#include <hip/hip_runtime.h>
#include <hip/hip_bf16.h>

#define N_NODES 50000
#define N_EDGES 600000
#define N_GRAPHS 64
#define HID 128
#define NLAYERS 4
#define IN_DIM 5
#define NCLS 5
#define EPS 1e-5f
#define SCAN_BLK ((N_NODES + 511) / 512)
#define POOL_CHUNKS 16
#define HLS 132   // fp32 Hl row stride (layer-0 kernel)
#define BSLOT 64  // BN-stat atomic slots
#define WS 136    // bf16 LDS row strides (MFMA kernel): 136*2B=272B -> even bank spread

typedef __attribute__((ext_vector_type(8))) short s16x8;
typedef __attribute__((ext_vector_type(4))) float f32x4;

// bf16 helpers (RNE)
__device__ __forceinline__ unsigned short f2bf(float x) {
    unsigned u = __float_as_uint(x);
    unsigned r = (u + 0x7fffu + ((u >> 16) & 1u)) >> 16;
    return (unsigned short)r;
}
__device__ __forceinline__ float2 bfpair(unsigned u) {
    float2 r;
    r.x = __uint_as_float(u << 16);
    r.y = __uint_as_float(u & 0xffff0000u);
    return r;
}
__device__ __forceinline__ float bf2f(unsigned short s) {
    return __uint_as_float(((unsigned)s) << 16);
}

// ---------------- CSR build ----------------

__global__ void k_count(const int* __restrict__ dst, int* __restrict__ cnt) {
    int i = blockIdx.x * blockDim.x + threadIdx.x;
    if (i < N_EDGES) atomicAdd(&cnt[dst[i]], 1);
}

__global__ void k_scan1(const int* __restrict__ cnt, int* __restrict__ rp, int* __restrict__ bsum) {
    __shared__ int s[512];
    int t = threadIdx.x;
    int i = blockIdx.x * 512 + t;
    int v = (i < N_NODES) ? cnt[i] : 0;
    s[t] = v;
    __syncthreads();
    for (int off = 1; off < 512; off <<= 1) {
        int x = (t >= off) ? s[t - off] : 0;
        __syncthreads();
        s[t] += x;
        __syncthreads();
    }
    if (i < N_NODES) rp[i + 1] = s[t];
    if (t == 511) bsum[blockIdx.x] = s[511];
}

__global__ void k_scan2g(int* __restrict__ bsum, const int* __restrict__ batch,
                         int* __restrict__ gstart) {
    if (blockIdx.x == 0) {
        __shared__ int s[128];
        int t = threadIdx.x;
        int v = (t < SCAN_BLK) ? bsum[t] : 0;
        s[t] = v;
        __syncthreads();
        for (int off = 1; off < 128; off <<= 1) {
            int x = (t >= off) ? s[t - off] : 0;
            __syncthreads();
            s[t] += x;
            __syncthreads();
        }
        if (t < SCAN_BLK) bsum[t] = s[t] - v;
    } else {
        int t = threadIdx.x;
        if (t <= N_GRAPHS) {
            int lo = 0, hi = N_NODES;
            while (lo < hi) {
                int mid = (lo + hi) >> 1;
                if (batch[mid] < t) lo = mid + 1; else hi = mid;
            }
            gstart[t] = lo;
        }
    }
}

__global__ void k_scan3d(int* __restrict__ rp, const int* __restrict__ bsum,
                         const int* __restrict__ cnt, float* __restrict__ dinv) {
    int i = blockIdx.x * 512 + threadIdx.x;
    if (i < N_NODES) {
        rp[i + 1] += bsum[blockIdx.x];
        dinv[i] = rsqrtf((float)(cnt[i] + 1));
    }
    if (i == 0) rp[0] = 0;
}

__global__ void k_fill(const int* __restrict__ src, const int* __restrict__ dst,
                       const int* __restrict__ rp, int* __restrict__ cursor,
                       int2* __restrict__ cw, const float* __restrict__ dinv) {
    int e = blockIdx.x * blockDim.x + threadIdx.x;
    if (e < N_EDGES) {
        int d = dst[e];
        int pos = atomicAdd(&cursor[d], 1);
        int s = src[e];
        int2 p;
        p.x = s;
        p.y = __float_as_int(dinv[s]);
        cw[rp[d] + pos] = p;
    }
}

// ---------------- layer 0 GEMM: Bm(bf16) = (x @ Wp + bp) @ W  (fp32 VALU) ----------------

__global__ __launch_bounds__(256) void k_gemm0(const float* __restrict__ x,
                                               const float* __restrict__ Wp,
                                               const float* __restrict__ bp,
                                               const float* __restrict__ W,
                                               unsigned short* __restrict__ Bm) {
    __shared__ float Wl[HID * 64];
    __shared__ float Hl[64 * HLS];
    __shared__ float xl[64 * IN_DIM];
    __shared__ float Wpl[IN_DIM * HID];
    __shared__ float bpl[HID];
    int t = threadIdx.x;
    int half = blockIdx.x & 1;
    int f0 = half * 64;
    {
        const float4* Wg4 = (const float4*)W;
        float4* Wl4 = (float4*)Wl;
        for (int idx = t; idx < HID * 16; idx += 256) {
            int k = idx >> 4, c = idx & 15;
            Wl4[idx] = Wg4[k * 32 + (f0 >> 2) + c];
        }
    }
    for (int idx = t; idx < IN_DIM * HID; idx += 256) Wpl[idx] = Wp[idx];
    if (t < HID) bpl[t] = bp[t];
    int fg = t & 15;
    int ng = t >> 4;
    int fl = fg * 4;
    const int numTiles = (N_NODES + 63) / 64;
    int stride = gridDim.x >> 1;
    for (int tile = blockIdx.x >> 1; tile < numTiles; tile += stride) {
        int n0 = tile * 64;
        __syncthreads();
        for (int idx = t; idx < 64 * IN_DIM; idx += 256) {
            int g = n0 * IN_DIM + idx;
            xl[idx] = (g < N_NODES * IN_DIM) ? x[g] : 0.f;
        }
        __syncthreads();
        for (int idx = t; idx < 64 * HID; idx += 256) {
            int n = idx >> 7, k = idx & 127;
            float acc = bpl[k];
#pragma unroll
            for (int j = 0; j < IN_DIM; j++) acc += xl[n * IN_DIM + j] * Wpl[j * HID + k];
            Hl[n * HLS + k] = acc;
        }
        __syncthreads();
        float acc[4][4];
#pragma unroll
        for (int j = 0; j < 4; j++)
#pragma unroll
            for (int c = 0; c < 4; c++) acc[j][c] = 0.f;
        for (int k = 0; k < HID; k += 4) {
            float4 w0 = *(const float4*)&Wl[(k + 0) * 64 + fl];
            float4 w1 = *(const float4*)&Wl[(k + 1) * 64 + fl];
            float4 w2 = *(const float4*)&Wl[(k + 2) * 64 + fl];
            float4 w3 = *(const float4*)&Wl[(k + 3) * 64 + fl];
#pragma unroll
            for (int j = 0; j < 4; j++) {
                float4 hv = *(const float4*)&Hl[(ng * 4 + j) * HLS + k];
                acc[j][0] += hv.x * w0.x + hv.y * w1.x + hv.z * w2.x + hv.w * w3.x;
                acc[j][1] += hv.x * w0.y + hv.y * w1.y + hv.z * w2.y + hv.w * w3.y;
                acc[j][2] += hv.x * w0.z + hv.y * w1.z + hv.z * w2.z + hv.w * w3.z;
                acc[j][3] += hv.x * w0.w + hv.y * w1.w + hv.z * w2.w + hv.w * w3.w;
            }
        }
#pragma unroll
        for (int j = 0; j < 4; j++) {
            int n = n0 + ng * 4 + j;
            if (n < N_NODES) {
                ushort4 o;
                o.x = f2bf(acc[j][0]);
                o.y = f2bf(acc[j][1]);
                o.z = f2bf(acc[j][2]);
                o.w = f2bf(acc[j][3]);
                *(ushort4*)&Bm[(size_t)n * HID + f0 + fl] = o;
            }
        }
    }
}

// ---------------- layers 1-3 GEMM: Bm(bf16) = relu(A*scale+shift) @ W  (MFMA) ----------------
// Block: 64 nodes x 128 cols. Wave w: rows 32*(w&1)..+32 (2x16), cols 64*(w>>1)..+64 (4x16).
// A-frag: A[m=lane&15][k=quad*8+j]; B-frag: B[k=quad*8+j][n=lane&15];
// C/D: row=quad*4+reg, col=lane&15.  W held transposed in LDS (Wt[n][k], stride 136).

__global__ __launch_bounds__(256) void k_gemmM(const unsigned short* __restrict__ Abf,
                                               const float* __restrict__ W,
                                               unsigned short* __restrict__ Bm,
                                               const float* __restrict__ scale,
                                               const float* __restrict__ shift) {
    __shared__ unsigned short Wt[HID * WS];
    __shared__ unsigned short Al[64 * WS];
    int t = threadIdx.x;
    for (int idx = t; idx < HID * HID; idx += 256) {
        int k = idx >> 7, n = idx & 127;
        Wt[n * WS + k] = f2bf(W[idx]);
    }
    int lane = t & 63, wv = t >> 6;
    int rbase = (wv & 1) * 32;
    int cbase = (wv >> 1) * 64;
    int mr = lane & 15, q = lane >> 4;
    const int numTiles = (N_NODES + 63) / 64;
    for (int tile = blockIdx.x; tile < numTiles; tile += gridDim.x) {
        int n0 = tile * 64;
        __syncthreads();  // Al reuse-safe; also orders first-iter Wt writes
        {
            const uint2* Ag = (const uint2*)(Abf + (size_t)n0 * HID);
            int limRow = min(64, N_NODES - n0);
            for (int idx = t; idx < 64 * 32; idx += 256) {
                int row = idx >> 5, c4 = idx & 31;
                uint2 u = (row < limRow) ? Ag[row * 32 + c4] : make_uint2(0u, 0u);
                float2 ab = bfpair(u.x);
                float2 cd = bfpair(u.y);
                int kf = c4 * 4;
                float4 sc = *(const float4*)&scale[kf];
                float4 sh = *(const float4*)&shift[kf];
                float v0 = fmaxf(ab.x * sc.x + sh.x, 0.f);
                float v1 = fmaxf(ab.y * sc.y + sh.y, 0.f);
                float v2 = fmaxf(cd.x * sc.z + sh.z, 0.f);
                float v3 = fmaxf(cd.y * sc.w + sh.w, 0.f);
                unsigned lo = (unsigned)f2bf(v0) | ((unsigned)f2bf(v1) << 16);
                unsigned hi = (unsigned)f2bf(v2) | ((unsigned)f2bf(v3) << 16);
                *(uint2*)&Al[row * WS + kf] = make_uint2(lo, hi);
            }
        }
        __syncthreads();
        f32x4 acc[2][4];
#pragma unroll
        for (int rt = 0; rt < 2; rt++)
#pragma unroll
            for (int ct = 0; ct < 4; ct++) acc[rt][ct] = (f32x4){0.f, 0.f, 0.f, 0.f};
#pragma unroll
        for (int kk = 0; kk < HID; kk += 32) {
            s16x8 a0 = *(const s16x8*)&Al[(rbase + mr) * WS + kk + q * 8];
            s16x8 a1 = *(const s16x8*)&Al[(rbase + 16 + mr) * WS + kk + q * 8];
#pragma unroll
            for (int ct = 0; ct < 4; ct++) {
                s16x8 b = *(const s16x8*)&Wt[(cbase + ct * 16 + mr) * WS + kk + q * 8];
                acc[0][ct] = __builtin_amdgcn_mfma_f32_16x16x32_bf16(a0, b, acc[0][ct], 0, 0, 0);
                acc[1][ct] = __builtin_amdgcn_mfma_f32_16x16x32_bf16(a1, b, acc[1][ct], 0, 0, 0);
            }
        }
#pragma unroll
        for (int rt = 0; rt < 2; rt++)
#pragma unroll
            for (int ct = 0; ct < 4; ct++)
#pragma unroll
                for (int r = 0; r < 4; r++) {
                    int node = n0 + rbase + rt * 16 + q * 4 + r;
                    if (node < N_NODES) {
                        int f = cbase + ct * 16 + mr;
                        Bm[(size_t)node * HID + f] = f2bf(acc[rt][ct][r]);
                    }
                }
    }
}

// ---------------- CSR gather + fused BN partial stats ----------------

__global__ __launch_bounds__(256) void k_gather(const unsigned int* __restrict__ Bmu,
                                                const int* __restrict__ rp,
                                                const int2* __restrict__ cw,
                                                const float* __restrict__ dinv,
                                                const float* __restrict__ bg,
                                                unsigned short* __restrict__ Aout,
                                                float* __restrict__ psum,
                                                float* __restrict__ psq) {
    __shared__ float ls[4 * HID], lq[4 * HID];
    int wave = threadIdx.x >> 6;
    int lane = threadIdx.x & 63;
    int v = blockIdx.x * 4 + wave;
    int beg = rp[v], end = rp[v + 1];
    float dv = dinv[v];
    float2 self = bfpair(Bmu[(size_t)v * 64 + lane]);
    float2 acc = make_float2(self.x * dv, self.y * dv);
    int e = beg;
    for (; e + 3 < end; e += 4) {
        int2 p0 = cw[e];
        int2 p1 = cw[e + 1];
        int2 p2 = cw[e + 2];
        int2 p3 = cw[e + 3];
        unsigned u0 = Bmu[(size_t)p0.x * 64 + lane];
        unsigned u1 = Bmu[(size_t)p1.x * 64 + lane];
        unsigned u2 = Bmu[(size_t)p2.x * 64 + lane];
        unsigned u3 = Bmu[(size_t)p3.x * 64 + lane];
        float2 m0 = bfpair(u0);
        float2 m1 = bfpair(u1);
        float2 m2 = bfpair(u2);
        float2 m3 = bfpair(u3);
        float w0 = __int_as_float(p0.y), w1 = __int_as_float(p1.y);
        float w2 = __int_as_float(p2.y), w3 = __int_as_float(p3.y);
        acc.x += m0.x * w0 + m1.x * w1 + m2.x * w2 + m3.x * w3;
        acc.y += m0.y * w0 + m1.y * w1 + m2.y * w2 + m3.y * w3;
    }
    for (; e < end; e++) {
        int2 p = cw[e];
        float2 m = bfpair(Bmu[(size_t)p.x * 64 + lane]);
        float w = __int_as_float(p.y);
        acc.x += m.x * w;
        acc.y += m.y * w;
    }
    int f = lane * 2;
    ushort2 o;
    o.x = f2bf(acc.x * dv + bg[f]);
    o.y = f2bf(acc.y * dv + bg[f + 1]);
    ((ushort2*)Aout)[(size_t)v * 64 + lane] = o;
    // BN partial stats on the bf16-rounded values (what the next GEMM consumes)
    float vx = bf2f(o.x), vy = bf2f(o.y);
    ls[wave * HID + f] = vx;
    ls[wave * HID + f + 1] = vy;
    lq[wave * HID + f] = vx * vx;
    lq[wave * HID + f + 1] = vy * vy;
    __syncthreads();
    int tt = threadIdx.x;
    if (tt < HID) {
        float s = ls[tt] + ls[HID + tt] + ls[2 * HID + tt] + ls[3 * HID + tt];
        float s2 = lq[tt] + lq[HID + tt] + lq[2 * HID + tt] + lq[3 * HID + tt];
        int slot = blockIdx.x & (BSLOT - 1);
        atomicAdd(&psum[slot * HID + tt], s);
        atomicAdd(&psq[slot * HID + tt], s2);
    }
}

// ---------------- BN finalize (reduces 64 slots, re-zeroes them) ----------------

__global__ __launch_bounds__(128) void k_bnfin(float* __restrict__ psum,
                                               float* __restrict__ psq,
                                               const float* __restrict__ gamma,
                                               const float* __restrict__ beta,
                                               float* __restrict__ scale,
                                               float* __restrict__ shift) {
    int f = threadIdx.x;
    float s = 0.f, s2 = 0.f;
#pragma unroll 8
    for (int b = 0; b < BSLOT; b++) {
        s += psum[b * HID + f];
        s2 += psq[b * HID + f];
    }
#pragma unroll 8
    for (int b = 0; b < BSLOT; b++) {
        psum[b * HID + f] = 0.f;
        psq[b * HID + f] = 0.f;
    }
    const float invN = 1.f / (float)N_NODES;
    float mu = s * invN;
    float var = s2 * invN - mu * mu;
    float rs = rsqrtf(var + EPS) * gamma[f];
    scale[f] = rs;
    shift[f] = beta[f] - mu * rs;
}

// ---------------- segmented pooling, chunked (bf16 input) ----------------

__global__ __launch_bounds__(128) void k_pool(const unsigned short* __restrict__ A,
                                              const float* __restrict__ scale,
                                              const float* __restrict__ shift,
                                              const int* __restrict__ gstart,
                                              float* __restrict__ poolPart) {
    int g = blockIdx.x;
    int c = blockIdx.y;
    int f = threadIdx.x;
    int beg = gstart[g], end = gstart[g + 1];
    int len = end - beg;
    int per = (len + POOL_CHUNKS - 1) / POOL_CHUNKS;
    int s0 = beg + c * per;
    int s1 = min(s0 + per, end);
    float sc = scale[f], sh = shift[f];
    float sa = 0.f, sb = 0.f, ma = 0.f, mb = 0.f;
    int n = s0;
    for (; n + 1 < s1; n += 2) {
        float v0 = bf2f(A[(size_t)n * HID + f]);
        float v1 = bf2f(A[(size_t)(n + 1) * HID + f]);
        v0 = fmaxf(v0 * sc + sh, 0.f);
        v1 = fmaxf(v1 * sc + sh, 0.f);
        sa += v0; ma = fmaxf(ma, v0);
        sb += v1; mb = fmaxf(mb, v1);
    }
    if (n < s1) {
        float v = fmaxf(bf2f(A[(size_t)n * HID + f]) * sc + sh, 0.f);
        sa += v; ma = fmaxf(ma, v);
    }
    poolPart[((size_t)g * POOL_CHUNKS + c) * 256 + f] = sa + sb;
    poolPart[((size_t)g * POOL_CHUNKS + c) * 256 + 128 + f] = fmaxf(ma, mb);
}

// ---------------- MLP head ----------------

__global__ __launch_bounds__(128) void k_head(const float* __restrict__ poolPart,
                                              const int* __restrict__ gstart,
                                              const float* __restrict__ W1, const float* __restrict__ b1,
                                              const float* __restrict__ W2, const float* __restrict__ b2,
                                              const float* __restrict__ W3, const float* __restrict__ b3,
                                              float* __restrict__ out) {
    __shared__ float pl[2 * HID];
    __shared__ float h1[HID];
    __shared__ float h2[HID / 2];
    int g = blockIdx.x, t = threadIdx.x;
    float cnt = fmaxf((float)(gstart[g + 1] - gstart[g]), 1.f);
    float s = 0.f, mx = 0.f;
#pragma unroll
    for (int c = 0; c < POOL_CHUNKS; c++) {
        const float* p = &poolPart[((size_t)g * POOL_CHUNKS + c) * 256];
        s += p[t];
        mx = fmaxf(mx, p[128 + t]);
    }
    pl[t] = s / cnt;
    pl[HID + t] = mx;
    __syncthreads();
    float acc = b1[t];
    for (int k = 0; k < 2 * HID; k++) acc += pl[k] * W1[k * HID + t];
    h1[t] = fmaxf(acc, 0.f);
    __syncthreads();
    if (t < HID / 2) {
        float a2 = b2[t];
        for (int k = 0; k < HID; k++) a2 += h1[k] * W2[k * (HID / 2) + t];
        h2[t] = fmaxf(a2, 0.f);
    }
    __syncthreads();
    if (t < NCLS) {
        float a3 = b3[t];
        for (int k = 0; k < HID / 2; k++) a3 += h2[k] * W3[k * NCLS + t];
        out[g * NCLS + t] = a3;
    }
}

extern "C" void kernel_launch(void* const* d_in, const int* in_sizes, int n_in,
                              void* d_out, int out_size, void* d_ws, size_t ws_size,
                              hipStream_t stream) {
    const float* x     = (const float*)d_in[0];
    const int*   ei    = (const int*)d_in[1];
    const int*   batch = (const int*)d_in[2];
    const float* Wp    = (const float*)d_in[3];
    const float* bp    = (const float*)d_in[4];
    const float* Wg    = (const float*)d_in[5];
    const float* bg    = (const float*)d_in[6];
    const float* gamma = (const float*)d_in[7];
    const float* beta  = (const float*)d_in[8];
    const float* W1    = (const float*)d_in[9];
    const float* b1    = (const float*)d_in[10];
    const float* W2    = (const float*)d_in[11];
    const float* b2    = (const float*)d_in[12];
    const float* W3    = (const float*)d_in[13];
    const float* b3    = (const float*)d_in[14];
    const int* src = ei;
    const int* dst = ei + N_EDGES;
    float* out = (float*)d_out;

    char* base = (char*)d_ws;
    size_t off = 0;
    auto alloc = [&](size_t bytes) -> void* {
        void* p = base + off;
        off += (bytes + 255) & ~(size_t)255;
        return p;
    };
    // zeroed region (one memset)
    int*   counts = (int*)alloc((size_t)N_NODES * 4);
    int*   cursor = (int*)alloc((size_t)N_NODES * 4);
    float* psum   = (float*)alloc((size_t)BSLOT * HID * 4);
    float* psq    = (float*)alloc((size_t)BSLOT * HID * 4);
    size_t zeroBytes = off;
    // non-zeroed scratch
    int*   rp      = (int*)alloc((size_t)(N_NODES + 1) * 4);
    int*   bsum    = (int*)alloc(128 * 4);
    int2*  cw      = (int2*)alloc((size_t)N_EDGES * 8);
    float* dinv    = (float*)alloc((size_t)N_NODES * 4);
    float* scaleA  = (float*)alloc((size_t)NLAYERS * HID * 4);
    float* shiftA  = (float*)alloc((size_t)NLAYERS * HID * 4);
    int*   gstart  = (int*)alloc((size_t)(N_GRAPHS + 1) * 4);
    float* poolPart= (float*)alloc((size_t)N_GRAPHS * POOL_CHUNKS * 256 * 4);
    unsigned short* A = (unsigned short*)alloc((size_t)N_NODES * HID * 2);
    unsigned short* B = (unsigned short*)alloc((size_t)N_NODES * HID * 2);
    (void)ws_size; (void)in_sizes; (void)n_in; (void)out_size;

    hipMemsetAsync(d_ws, 0, zeroBytes, stream);

    k_count<<<(N_EDGES + 255) / 256, 256, 0, stream>>>(dst, counts);
    k_scan1<<<SCAN_BLK, 512, 0, stream>>>(counts, rp, bsum);
    k_scan2g<<<2, 128, 0, stream>>>(bsum, batch, gstart);
    k_scan3d<<<SCAN_BLK, 512, 0, stream>>>(rp, bsum, counts, dinv);
    k_fill<<<(N_EDGES + 255) / 256, 256, 0, stream>>>(src, dst, rp, cursor, cw, dinv);

    for (int i = 0; i < NLAYERS; i++) {
        if (i == 0) {
            k_gemm0<<<1024, 256, 0, stream>>>(x, Wp, bp, Wg, B);
        } else {
            k_gemmM<<<768, 256, 0, stream>>>(A, Wg + (size_t)i * HID * HID, B,
                                             scaleA + (i - 1) * HID, shiftA + (i - 1) * HID);
        }
        k_gather<<<N_NODES / 4, 256, 0, stream>>>((const unsigned int*)B, rp, cw, dinv,
                                                  bg + i * HID, A, psum, psq);
        k_bnfin<<<1, 128, 0, stream>>>(psum, psq, gamma + i * HID, beta + i * HID,
                                       scaleA + i * HID, shiftA + i * HID);
    }
    dim3 pg(N_GRAPHS, POOL_CHUNKS);
    k_pool<<<pg, 128, 0, stream>>>(A, scaleA + 3 * HID, shiftA + 3 * HID, gstart, poolPart);
    k_head<<<N_GRAPHS, 128, 0, stream>>>(poolPart, gstart, W1, b1, W2, b2, W3, b3, out);
}

// Round 7
// 435.515 us; speedup vs baseline: 2.6459x; 1.0337x over previous
//
#include <hip/hip_runtime.h>
#include <hip/hip_bf16.h>

#define N_NODES 50000
#define N_EDGES 600000
#define N_GRAPHS 64
#define HID 128
#define NLAYERS 4
#define IN_DIM 5
#define NCLS 5
#define EPS 1e-5f
#define SCAN_BLK ((N_NODES + 511) / 512)
#define POOL_CHUNKS 16
#define BSLOT 64  // BN-stat atomic slots
#define WS 136    // bf16 LDS row stride (MFMA kernel)

typedef __attribute__((ext_vector_type(8))) short s16x8;
typedef __attribute__((ext_vector_type(4))) float f32x4;

// bf16 helpers (RNE)
__device__ __forceinline__ unsigned short f2bf(float x) {
    unsigned u = __float_as_uint(x);
    unsigned r = (u + 0x7fffu + ((u >> 16) & 1u)) >> 16;
    return (unsigned short)r;
}
__device__ __forceinline__ float2 bfpair(unsigned u) {
    float2 r;
    r.x = __uint_as_float(u << 16);
    r.y = __uint_as_float(u & 0xffff0000u);
    return r;
}
__device__ __forceinline__ float bf2f(unsigned short s) {
    return __uint_as_float(((unsigned)s) << 16);
}

// ---------------- CSR build ----------------

__global__ void k_count(const int* __restrict__ dst, int* __restrict__ cnt) {
    int i = blockIdx.x * blockDim.x + threadIdx.x;
    if (i < N_EDGES) atomicAdd(&cnt[dst[i]], 1);
}

__global__ void k_scan1(const int* __restrict__ cnt, int* __restrict__ rp, int* __restrict__ bsum) {
    __shared__ int s[512];
    int t = threadIdx.x;
    int i = blockIdx.x * 512 + t;
    int v = (i < N_NODES) ? cnt[i] : 0;
    s[t] = v;
    __syncthreads();
    for (int off = 1; off < 512; off <<= 1) {
        int x = (t >= off) ? s[t - off] : 0;
        __syncthreads();
        s[t] += x;
        __syncthreads();
    }
    if (i < N_NODES) rp[i + 1] = s[t];
    if (t == 511) bsum[blockIdx.x] = s[511];
}

__global__ void k_scan2g(int* __restrict__ bsum, const int* __restrict__ batch,
                         int* __restrict__ gstart) {
    if (blockIdx.x == 0) {
        __shared__ int s[128];
        int t = threadIdx.x;
        int v = (t < SCAN_BLK) ? bsum[t] : 0;
        s[t] = v;
        __syncthreads();
        for (int off = 1; off < 128; off <<= 1) {
            int x = (t >= off) ? s[t - off] : 0;
            __syncthreads();
            s[t] += x;
            __syncthreads();
        }
        if (t < SCAN_BLK) bsum[t] = s[t] - v;
    } else {
        int t = threadIdx.x;
        if (t <= N_GRAPHS) {
            int lo = 0, hi = N_NODES;
            while (lo < hi) {
                int mid = (lo + hi) >> 1;
                if (batch[mid] < t) lo = mid + 1; else hi = mid;
            }
            gstart[t] = lo;
        }
    }
}

__global__ void k_scan3d(int* __restrict__ rp, const int* __restrict__ bsum,
                         const int* __restrict__ cnt, float* __restrict__ dinv) {
    int i = blockIdx.x * 512 + threadIdx.x;
    if (i < N_NODES) {
        rp[i + 1] += bsum[blockIdx.x];
        dinv[i] = rsqrtf((float)(cnt[i] + 1));
    }
    if (i == 0) rp[0] = 0;
}

__global__ void k_fill(const int* __restrict__ src, const int* __restrict__ dst,
                       const int* __restrict__ rp, int* __restrict__ cursor,
                       int2* __restrict__ cw, const float* __restrict__ dinv) {
    int e = blockIdx.x * blockDim.x + threadIdx.x;
    if (e < N_EDGES) {
        int d = dst[e];
        int pos = atomicAdd(&cursor[d], 1);
        int s = src[e];
        int2 p;
        p.x = s;
        p.y = __float_as_int(dinv[s]);
        cw[rp[d] + pos] = p;
    }
}

// ---------------- GEMM (MFMA): Bm(bf16) = act(in) @ W ----------------
// layer0: in = x @ Wp + bp (computed per tile, bf16-quantized into Al)
// else:   in = relu(A*scale+shift) (prev layer's BN+ReLU folded into staging)
// Block: 64 nodes x 128 cols. Wave w: rows 32*(w&1), cols 64*(w>>1).
// A-frag: A[m=lane&15][k=quad*8+j]; B-frag: B[k=quad*8+j][n=lane&15];
// C/D: row=quad*4+reg, col=lane&15.  W transposed in LDS (Wt[n][k], stride WS).

__global__ __launch_bounds__(256) void k_gemmM(const unsigned short* __restrict__ Abf,
                                               const float* __restrict__ x,
                                               const float* __restrict__ Wp,
                                               const float* __restrict__ bp,
                                               const float* __restrict__ W,
                                               unsigned short* __restrict__ Bm,
                                               const float* __restrict__ scale,
                                               const float* __restrict__ shift,
                                               int layer0) {
    __shared__ unsigned short Wt[HID * WS];
    __shared__ unsigned short Al[64 * WS];
    __shared__ float Wpl[IN_DIM * HID];
    __shared__ float bpl[HID];
    __shared__ float xl[64 * IN_DIM];
    int t = threadIdx.x;
    for (int idx = t; idx < HID * HID; idx += 256) {
        int k = idx >> 7, n = idx & 127;
        Wt[n * WS + k] = f2bf(W[idx]);
    }
    if (layer0) {
        for (int idx = t; idx < IN_DIM * HID; idx += 256) Wpl[idx] = Wp[idx];
        if (t < HID) bpl[t] = bp[t];
    }
    int lane = t & 63, wv = t >> 6;
    int rbase = (wv & 1) * 32;
    int cbase = (wv >> 1) * 64;
    int mr = lane & 15, q = lane >> 4;
    const int numTiles = (N_NODES + 63) / 64;
    for (int tile = blockIdx.x; tile < numTiles; tile += gridDim.x) {
        int n0 = tile * 64;
        __syncthreads();  // Al reuse-safe; also orders first-iter Wt/Wpl writes
        if (layer0) {
            for (int idx = t; idx < 64 * IN_DIM; idx += 256) {
                int g = n0 * IN_DIM + idx;
                xl[idx] = (g < N_NODES * IN_DIM) ? x[g] : 0.f;
            }
            __syncthreads();
            for (int idx = t; idx < 64 * HID; idx += 256) {
                int n = idx >> 7, k = idx & 127;
                float acc = bpl[k];
#pragma unroll
                for (int j = 0; j < IN_DIM; j++) acc += xl[n * IN_DIM + j] * Wpl[j * HID + k];
                Al[n * WS + k] = f2bf(acc);
            }
        } else {
            const uint2* Ag = (const uint2*)(Abf + (size_t)n0 * HID);
            int limRow = min(64, N_NODES - n0);
            for (int idx = t; idx < 64 * 32; idx += 256) {
                int row = idx >> 5, c4 = idx & 31;
                uint2 u = (row < limRow) ? Ag[row * 32 + c4] : make_uint2(0u, 0u);
                float2 ab = bfpair(u.x);
                float2 cd = bfpair(u.y);
                int kf = c4 * 4;
                float4 sc = *(const float4*)&scale[kf];
                float4 sh = *(const float4*)&shift[kf];
                float v0 = fmaxf(ab.x * sc.x + sh.x, 0.f);
                float v1 = fmaxf(ab.y * sc.y + sh.y, 0.f);
                float v2 = fmaxf(cd.x * sc.z + sh.z, 0.f);
                float v3 = fmaxf(cd.y * sc.w + sh.w, 0.f);
                unsigned lo = (unsigned)f2bf(v0) | ((unsigned)f2bf(v1) << 16);
                unsigned hi = (unsigned)f2bf(v2) | ((unsigned)f2bf(v3) << 16);
                *(uint2*)&Al[row * WS + kf] = make_uint2(lo, hi);
            }
        }
        __syncthreads();
        f32x4 acc[2][4];
#pragma unroll
        for (int rt = 0; rt < 2; rt++)
#pragma unroll
            for (int ct = 0; ct < 4; ct++) acc[rt][ct] = (f32x4){0.f, 0.f, 0.f, 0.f};
#pragma unroll
        for (int kk = 0; kk < HID; kk += 32) {
            s16x8 a0 = *(const s16x8*)&Al[(rbase + mr) * WS + kk + q * 8];
            s16x8 a1 = *(const s16x8*)&Al[(rbase + 16 + mr) * WS + kk + q * 8];
#pragma unroll
            for (int ct = 0; ct < 4; ct++) {
                s16x8 b = *(const s16x8*)&Wt[(cbase + ct * 16 + mr) * WS + kk + q * 8];
                acc[0][ct] = __builtin_amdgcn_mfma_f32_16x16x32_bf16(a0, b, acc[0][ct], 0, 0, 0);
                acc[1][ct] = __builtin_amdgcn_mfma_f32_16x16x32_bf16(a1, b, acc[1][ct], 0, 0, 0);
            }
        }
#pragma unroll
        for (int rt = 0; rt < 2; rt++)
#pragma unroll
            for (int ct = 0; ct < 4; ct++)
#pragma unroll
                for (int r = 0; r < 4; r++) {
                    int node = n0 + rbase + rt * 16 + q * 4 + r;
                    if (node < N_NODES) {
                        int f = cbase + ct * 16 + mr;
                        Bm[(size_t)node * HID + f] = f2bf(acc[rt][ct][r]);
                    }
                }
    }
}

// ---------------- CSR gather + fused BN partial stats ----------------
// One wave per node; two 32-lane halves each fetch a DIFFERENT edge's row
// (uint2/lane = 256B/row, 512B per wave instruction = 2 rows). Halves are
// combined with shfl_xor(32). Unroll x2 -> 4 rows in flight per wave.

__global__ __launch_bounds__(256) void k_gather(const uint2* __restrict__ Bm2,
                                                const int* __restrict__ rp,
                                                const int2* __restrict__ cw,
                                                const float* __restrict__ dinv,
                                                const float* __restrict__ bg,
                                                unsigned short* __restrict__ Aout,
                                                float* __restrict__ psum,
                                                float* __restrict__ psq) {
    __shared__ float ls[4 * HID], lq[4 * HID];
    int wave = threadIdx.x >> 6;
    int lane = threadIdx.x & 63;
    int s = lane & 31;   // feature quad: features s*4 .. s*4+3
    int p = lane >> 5;   // half-wave: edges beg+p, beg+p+2, ...
    int v = blockIdx.x * 4 + wave;
    int beg = rp[v], end = rp[v + 1];
    float dv = dinv[v];
    float4 acc = make_float4(0.f, 0.f, 0.f, 0.f);
    if (p == 0) {  // self-loop term
        uint2 u = Bm2[(size_t)v * 32 + s];
        float2 lo = bfpair(u.x), hi = bfpair(u.y);
        acc.x = lo.x * dv; acc.y = lo.y * dv; acc.z = hi.x * dv; acc.w = hi.y * dv;
    }
    int e = beg + p;
    for (; e + 2 < end; e += 4) {
        int2 pe0 = cw[e];
        int2 pe1 = cw[e + 2];
        uint2 u0 = Bm2[(size_t)pe0.x * 32 + s];
        uint2 u1 = Bm2[(size_t)pe1.x * 32 + s];
        float w0 = __int_as_float(pe0.y);
        float w1 = __int_as_float(pe1.y);
        float2 l0 = bfpair(u0.x), h0 = bfpair(u0.y);
        float2 l1 = bfpair(u1.x), h1 = bfpair(u1.y);
        acc.x += l0.x * w0 + l1.x * w1;
        acc.y += l0.y * w0 + l1.y * w1;
        acc.z += h0.x * w0 + h1.x * w1;
        acc.w += h0.y * w0 + h1.y * w1;
    }
    if (e < end) {
        int2 pe = cw[e];
        uint2 u = Bm2[(size_t)pe.x * 32 + s];
        float w = __int_as_float(pe.y);
        float2 lo = bfpair(u.x), hi = bfpair(u.y);
        acc.x += lo.x * w; acc.y += lo.y * w; acc.z += hi.x * w; acc.w += hi.y * w;
    }
    // combine the two halves
    acc.x += __shfl_xor(acc.x, 32);
    acc.y += __shfl_xor(acc.y, 32);
    acc.z += __shfl_xor(acc.z, 32);
    acc.w += __shfl_xor(acc.w, 32);
    int f = s * 4;
    if (p == 0) {
        float4 bgv = *(const float4*)&bg[f];
        ushort4 o;
        o.x = f2bf(acc.x * dv + bgv.x);
        o.y = f2bf(acc.y * dv + bgv.y);
        o.z = f2bf(acc.z * dv + bgv.z);
        o.w = f2bf(acc.w * dv + bgv.w);
        *(ushort4*)&Aout[(size_t)v * HID + f] = o;
        // BN partial stats on the bf16-rounded values (what the next GEMM sees)
        float vx = bf2f(o.x), vy = bf2f(o.y), vz = bf2f(o.z), vw = bf2f(o.w);
        ls[wave * HID + f + 0] = vx;
        ls[wave * HID + f + 1] = vy;
        ls[wave * HID + f + 2] = vz;
        ls[wave * HID + f + 3] = vw;
        lq[wave * HID + f + 0] = vx * vx;
        lq[wave * HID + f + 1] = vy * vy;
        lq[wave * HID + f + 2] = vz * vz;
        lq[wave * HID + f + 3] = vw * vw;
    }
    __syncthreads();
    int tt = threadIdx.x;
    if (tt < HID) {
        float ssum = ls[tt] + ls[HID + tt] + ls[2 * HID + tt] + ls[3 * HID + tt];
        float ssq = lq[tt] + lq[HID + tt] + lq[2 * HID + tt] + lq[3 * HID + tt];
        int slot = blockIdx.x & (BSLOT - 1);
        atomicAdd(&psum[slot * HID + tt], ssum);
        atomicAdd(&psq[slot * HID + tt], ssq);
    }
}

// ---------------- BN finalize (reduces 64 slots, re-zeroes them) ----------------

__global__ __launch_bounds__(128) void k_bnfin(float* __restrict__ psum,
                                               float* __restrict__ psq,
                                               const float* __restrict__ gamma,
                                               const float* __restrict__ beta,
                                               float* __restrict__ scale,
                                               float* __restrict__ shift) {
    int f = threadIdx.x;
    float s = 0.f, s2 = 0.f;
#pragma unroll 8
    for (int b = 0; b < BSLOT; b++) {
        s += psum[b * HID + f];
        s2 += psq[b * HID + f];
    }
#pragma unroll 8
    for (int b = 0; b < BSLOT; b++) {
        psum[b * HID + f] = 0.f;
        psq[b * HID + f] = 0.f;
    }
    const float invN = 1.f / (float)N_NODES;
    float mu = s * invN;
    float var = s2 * invN - mu * mu;
    float rs = rsqrtf(var + EPS) * gamma[f];
    scale[f] = rs;
    shift[f] = beta[f] - mu * rs;
}

// ---------------- segmented pooling, chunked (bf16 input) ----------------

__global__ __launch_bounds__(128) void k_pool(const unsigned short* __restrict__ A,
                                              const float* __restrict__ scale,
                                              const float* __restrict__ shift,
                                              const int* __restrict__ gstart,
                                              float* __restrict__ poolPart) {
    int g = blockIdx.x;
    int c = blockIdx.y;
    int f = threadIdx.x;
    int beg = gstart[g], end = gstart[g + 1];
    int len = end - beg;
    int per = (len + POOL_CHUNKS - 1) / POOL_CHUNKS;
    int s0 = beg + c * per;
    int s1 = min(s0 + per, end);
    float sc = scale[f], sh = shift[f];
    float sa = 0.f, sb = 0.f, ma = 0.f, mb = 0.f;
    int n = s0;
    for (; n + 1 < s1; n += 2) {
        float v0 = bf2f(A[(size_t)n * HID + f]);
        float v1 = bf2f(A[(size_t)(n + 1) * HID + f]);
        v0 = fmaxf(v0 * sc + sh, 0.f);
        v1 = fmaxf(v1 * sc + sh, 0.f);
        sa += v0; ma = fmaxf(ma, v0);
        sb += v1; mb = fmaxf(mb, v1);
    }
    if (n < s1) {
        float v = fmaxf(bf2f(A[(size_t)n * HID + f]) * sc + sh, 0.f);
        sa += v; ma = fmaxf(ma, v);
    }
    poolPart[((size_t)g * POOL_CHUNKS + c) * 256 + f] = sa + sb;
    poolPart[((size_t)g * POOL_CHUNKS + c) * 256 + 128 + f] = fmaxf(ma, mb);
}

// ---------------- MLP head ----------------

__global__ __launch_bounds__(128) void k_head(const float* __restrict__ poolPart,
                                              const int* __restrict__ gstart,
                                              const float* __restrict__ W1, const float* __restrict__ b1,
                                              const float* __restrict__ W2, const float* __restrict__ b2,
                                              const float* __restrict__ W3, const float* __restrict__ b3,
                                              float* __restrict__ out) {
    __shared__ float pl[2 * HID];
    __shared__ float h1[HID];
    __shared__ float h2[HID / 2];
    int g = blockIdx.x, t = threadIdx.x;
    float cnt = fmaxf((float)(gstart[g + 1] - gstart[g]), 1.f);
    float s = 0.f, mx = 0.f;
#pragma unroll
    for (int c = 0; c < POOL_CHUNKS; c++) {
        const float* p = &poolPart[((size_t)g * POOL_CHUNKS + c) * 256];
        s += p[t];
        mx = fmaxf(mx, p[128 + t]);
    }
    pl[t] = s / cnt;
    pl[HID + t] = mx;
    __syncthreads();
    float acc = b1[t];
    for (int k = 0; k < 2 * HID; k++) acc += pl[k] * W1[k * HID + t];
    h1[t] = fmaxf(acc, 0.f);
    __syncthreads();
    if (t < HID / 2) {
        float a2 = b2[t];
        for (int k = 0; k < HID; k++) a2 += h1[k] * W2[k * (HID / 2) + t];
        h2[t] = fmaxf(a2, 0.f);
    }
    __syncthreads();
    if (t < NCLS) {
        float a3 = b3[t];
        for (int k = 0; k < HID / 2; k++) a3 += h2[k] * W3[k * NCLS + t];
        out[g * NCLS + t] = a3;
    }
}

extern "C" void kernel_launch(void* const* d_in, const int* in_sizes, int n_in,
                              void* d_out, int out_size, void* d_ws, size_t ws_size,
                              hipStream_t stream) {
    const float* x     = (const float*)d_in[0];
    const int*   ei    = (const int*)d_in[1];
    const int*   batch = (const int*)d_in[2];
    const float* Wp    = (const float*)d_in[3];
    const float* bp    = (const float*)d_in[4];
    const float* Wg    = (const float*)d_in[5];
    const float* bg    = (const float*)d_in[6];
    const float* gamma = (const float*)d_in[7];
    const float* beta  = (const float*)d_in[8];
    const float* W1    = (const float*)d_in[9];
    const float* b1    = (const float*)d_in[10];
    const float* W2    = (const float*)d_in[11];
    const float* b2    = (const float*)d_in[12];
    const float* W3    = (const float*)d_in[13];
    const float* b3    = (const float*)d_in[14];
    const int* src = ei;
    const int* dst = ei + N_EDGES;
    float* out = (float*)d_out;

    char* base = (char*)d_ws;
    size_t off = 0;
    auto alloc = [&](size_t bytes) -> void* {
        void* p = base + off;
        off += (bytes + 255) & ~(size_t)255;
        return p;
    };
    // zeroed region (one memset)
    int*   counts = (int*)alloc((size_t)N_NODES * 4);
    int*   cursor = (int*)alloc((size_t)N_NODES * 4);
    float* psum   = (float*)alloc((size_t)BSLOT * HID * 4);
    float* psq    = (float*)alloc((size_t)BSLOT * HID * 4);
    size_t zeroBytes = off;
    // non-zeroed scratch
    int*   rp      = (int*)alloc((size_t)(N_NODES + 1) * 4);
    int*   bsum    = (int*)alloc(128 * 4);
    int2*  cw      = (int2*)alloc((size_t)N_EDGES * 8);
    float* dinv    = (float*)alloc((size_t)N_NODES * 4);
    float* scaleA  = (float*)alloc((size_t)NLAYERS * HID * 4);
    float* shiftA  = (float*)alloc((size_t)NLAYERS * HID * 4);
    int*   gstart  = (int*)alloc((size_t)(N_GRAPHS + 1) * 4);
    float* poolPart= (float*)alloc((size_t)N_GRAPHS * POOL_CHUNKS * 256 * 4);
    unsigned short* A = (unsigned short*)alloc((size_t)N_NODES * HID * 2);
    unsigned short* B = (unsigned short*)alloc((size_t)N_NODES * HID * 2);
    (void)ws_size; (void)in_sizes; (void)n_in; (void)out_size;

    hipMemsetAsync(d_ws, 0, zeroBytes, stream);

    k_count<<<(N_EDGES + 255) / 256, 256, 0, stream>>>(dst, counts);
    k_scan1<<<SCAN_BLK, 512, 0, stream>>>(counts, rp, bsum);
    k_scan2g<<<2, 128, 0, stream>>>(bsum, batch, gstart);
    k_scan3d<<<SCAN_BLK, 512, 0, stream>>>(rp, bsum, counts, dinv);
    k_fill<<<(N_EDGES + 255) / 256, 256, 0, stream>>>(src, dst, rp, cursor, cw, dinv);

    for (int i = 0; i < NLAYERS; i++) {
        k_gemmM<<<768, 256, 0, stream>>>(A, x, Wp, bp, Wg + (size_t)i * HID * HID, B,
                                         scaleA + ((i == 0) ? 0 : (i - 1)) * HID,
                                         shiftA + ((i == 0) ? 0 : (i - 1)) * HID,
                                         (i == 0) ? 1 : 0);
        k_gather<<<N_NODES / 4, 256, 0, stream>>>((const uint2*)B, rp, cw, dinv,
                                                  bg + i * HID, A, psum, psq);
        k_bnfin<<<1, 128, 0, stream>>>(psum, psq, gamma + i * HID, beta + i * HID,
                                       scaleA + i * HID, shiftA + i * HID);
    }
    dim3 pg(N_GRAPHS, POOL_CHUNKS);
    k_pool<<<pg, 128, 0, stream>>>(A, scaleA + 3 * HID, shiftA + 3 * HID, gstart, poolPart);
    k_head<<<N_GRAPHS, 128, 0, stream>>>(poolPart, gstart, W1, b1, W2, b2, W3, b3, out);
}

// Round 8
// 411.160 us; speedup vs baseline: 2.8026x; 1.0592x over previous
//
#include <hip/hip_runtime.h>
#include <hip/hip_bf16.h>

#define N_NODES 50000
#define N_EDGES 600000
#define N_GRAPHS 64
#define HID 128
#define NLAYERS 4
#define IN_DIM 5
#define NCLS 5
#define EPS 1e-5f
#define SCAN_BLK ((N_NODES + 511) / 512)
#define POOL_CHUNKS 16
#define BSLOT 64  // BN-stat atomic slots (per layer)
#define WS 136    // bf16 LDS row stride (MFMA kernel)

typedef __attribute__((ext_vector_type(8))) short s16x8;
typedef __attribute__((ext_vector_type(4))) float f32x4;

// bf16 helpers (RNE)
__device__ __forceinline__ unsigned short f2bf(float x) {
    unsigned u = __float_as_uint(x);
    unsigned r = (u + 0x7fffu + ((u >> 16) & 1u)) >> 16;
    return (unsigned short)r;
}
__device__ __forceinline__ float2 bfpair(unsigned u) {
    float2 r;
    r.x = __uint_as_float(u << 16);
    r.y = __uint_as_float(u & 0xffff0000u);
    return r;
}
__device__ __forceinline__ float bf2f(unsigned short s) {
    return __uint_as_float(((unsigned)s) << 16);
}

// ---------------- CSR build ----------------

__global__ void k_count(const int* __restrict__ dst, int* __restrict__ cnt) {
    int i = blockIdx.x * blockDim.x + threadIdx.x;
    if (i < N_EDGES) atomicAdd(&cnt[dst[i]], 1);
}

__global__ void k_scan1(const int* __restrict__ cnt, int* __restrict__ rp, int* __restrict__ bsum) {
    __shared__ int s[512];
    int t = threadIdx.x;
    int i = blockIdx.x * 512 + t;
    int v = (i < N_NODES) ? cnt[i] : 0;
    s[t] = v;
    __syncthreads();
    for (int off = 1; off < 512; off <<= 1) {
        int x = (t >= off) ? s[t - off] : 0;
        __syncthreads();
        s[t] += x;
        __syncthreads();
    }
    if (i < N_NODES) rp[i + 1] = s[t];
    if (t == 511) bsum[blockIdx.x] = s[511];
}

__global__ void k_scan2g(int* __restrict__ bsum, const int* __restrict__ batch,
                         int* __restrict__ gstart) {
    if (blockIdx.x == 0) {
        __shared__ int s[128];
        int t = threadIdx.x;
        int v = (t < SCAN_BLK) ? bsum[t] : 0;
        s[t] = v;
        __syncthreads();
        for (int off = 1; off < 128; off <<= 1) {
            int x = (t >= off) ? s[t - off] : 0;
            __syncthreads();
            s[t] += x;
            __syncthreads();
        }
        if (t < SCAN_BLK) bsum[t] = s[t] - v;
    } else {
        int t = threadIdx.x;
        if (t <= N_GRAPHS) {
            int lo = 0, hi = N_NODES;
            while (lo < hi) {
                int mid = (lo + hi) >> 1;
                if (batch[mid] < t) lo = mid + 1; else hi = mid;
            }
            gstart[t] = lo;
        }
    }
}

__global__ void k_scan3d(int* __restrict__ rp, const int* __restrict__ bsum,
                         const int* __restrict__ cnt, float* __restrict__ dinv) {
    int i = blockIdx.x * 512 + threadIdx.x;
    if (i < N_NODES) {
        rp[i + 1] += bsum[blockIdx.x];
        dinv[i] = rsqrtf((float)(cnt[i] + 1));
    }
    if (i == 0) rp[0] = 0;
}

__global__ void k_fill(const int* __restrict__ src, const int* __restrict__ dst,
                       const int* __restrict__ rp, int* __restrict__ cursor,
                       int2* __restrict__ cw, const float* __restrict__ dinv) {
    int e = blockIdx.x * blockDim.x + threadIdx.x;
    if (e < N_EDGES) {
        int d = dst[e];
        int pos = atomicAdd(&cursor[d], 1);
        int s = src[e];
        int2 p;
        p.x = s;
        p.y = __float_as_int(dinv[s]);
        cw[rp[d] + pos] = p;
    }
}

// ---------------- GEMM (MFMA): Bm(bf16) = act(in) @ W ----------------
// layer0: in = x @ Wp + bp (computed per tile). Else: in = relu(A*sc+sh),
// where sc/sh are derived IN-KERNEL from the previous gather's psum/psq slots.

__global__ __launch_bounds__(256) void k_gemmM(const unsigned short* __restrict__ Abf,
                                               const float* __restrict__ x,
                                               const float* __restrict__ Wp,
                                               const float* __restrict__ bp,
                                               const float* __restrict__ W,
                                               unsigned short* __restrict__ Bm,
                                               const float* __restrict__ psum,
                                               const float* __restrict__ psq,
                                               const float* __restrict__ gamma,
                                               const float* __restrict__ beta,
                                               int layer0) {
    __shared__ unsigned short Wt[HID * WS];
    __shared__ unsigned short Al[64 * WS];
    __shared__ float scl[HID], shf[HID];
    __shared__ float Wpl[IN_DIM * HID];
    __shared__ float bpl[HID];
    __shared__ float xl[64 * IN_DIM];
    int t = threadIdx.x;
    for (int idx = t; idx < HID * HID; idx += 256) {
        int k = idx >> 7, n = idx & 127;
        Wt[n * WS + k] = f2bf(W[idx]);
    }
    if (layer0) {
        for (int idx = t; idx < IN_DIM * HID; idx += 256) Wpl[idx] = Wp[idx];
        if (t < HID) bpl[t] = bp[t];
    } else if (t < HID) {
        float s = 0.f, s2 = 0.f;
#pragma unroll 8
        for (int b = 0; b < BSLOT; b++) {
            s += psum[b * HID + t];
            s2 += psq[b * HID + t];
        }
        const float invN = 1.f / (float)N_NODES;
        float mu = s * invN;
        float var = s2 * invN - mu * mu;
        float rs = rsqrtf(var + EPS) * gamma[t];
        scl[t] = rs;
        shf[t] = beta[t] - mu * rs;
    }
    int lane = t & 63, wv = t >> 6;
    int rbase = (wv & 1) * 32;
    int cbase = (wv >> 1) * 64;
    int mr = lane & 15, q = lane >> 4;
    const int numTiles = (N_NODES + 63) / 64;
    for (int tile = blockIdx.x; tile < numTiles; tile += gridDim.x) {
        int n0 = tile * 64;
        __syncthreads();  // orders scl/Wt writes (1st iter) + Al reuse safety
        if (layer0) {
            for (int idx = t; idx < 64 * IN_DIM; idx += 256) {
                int g = n0 * IN_DIM + idx;
                xl[idx] = (g < N_NODES * IN_DIM) ? x[g] : 0.f;
            }
            __syncthreads();
            for (int idx = t; idx < 64 * HID; idx += 256) {
                int n = idx >> 7, k = idx & 127;
                float acc = bpl[k];
#pragma unroll
                for (int j = 0; j < IN_DIM; j++) acc += xl[n * IN_DIM + j] * Wpl[j * HID + k];
                Al[n * WS + k] = f2bf(acc);
            }
        } else {
            const uint2* Ag = (const uint2*)(Abf + (size_t)n0 * HID);
            int limRow = min(64, N_NODES - n0);
            for (int idx = t; idx < 64 * 32; idx += 256) {
                int row = idx >> 5, c4 = idx & 31;
                uint2 u = (row < limRow) ? Ag[row * 32 + c4] : make_uint2(0u, 0u);
                float2 ab = bfpair(u.x);
                float2 cd = bfpair(u.y);
                int kf = c4 * 4;
                float4 sc = *(const float4*)&scl[kf];
                float4 sh = *(const float4*)&shf[kf];
                float v0 = fmaxf(ab.x * sc.x + sh.x, 0.f);
                float v1 = fmaxf(ab.y * sc.y + sh.y, 0.f);
                float v2 = fmaxf(cd.x * sc.z + sh.z, 0.f);
                float v3 = fmaxf(cd.y * sc.w + sh.w, 0.f);
                unsigned lo = (unsigned)f2bf(v0) | ((unsigned)f2bf(v1) << 16);
                unsigned hi = (unsigned)f2bf(v2) | ((unsigned)f2bf(v3) << 16);
                *(uint2*)&Al[row * WS + kf] = make_uint2(lo, hi);
            }
        }
        __syncthreads();
        f32x4 acc[2][4];
#pragma unroll
        for (int rt = 0; rt < 2; rt++)
#pragma unroll
            for (int ct = 0; ct < 4; ct++) acc[rt][ct] = (f32x4){0.f, 0.f, 0.f, 0.f};
#pragma unroll
        for (int kk = 0; kk < HID; kk += 32) {
            s16x8 a0 = *(const s16x8*)&Al[(rbase + mr) * WS + kk + q * 8];
            s16x8 a1 = *(const s16x8*)&Al[(rbase + 16 + mr) * WS + kk + q * 8];
#pragma unroll
            for (int ct = 0; ct < 4; ct++) {
                s16x8 b = *(const s16x8*)&Wt[(cbase + ct * 16 + mr) * WS + kk + q * 8];
                acc[0][ct] = __builtin_amdgcn_mfma_f32_16x16x32_bf16(a0, b, acc[0][ct], 0, 0, 0);
                acc[1][ct] = __builtin_amdgcn_mfma_f32_16x16x32_bf16(a1, b, acc[1][ct], 0, 0, 0);
            }
        }
#pragma unroll
        for (int rt = 0; rt < 2; rt++)
#pragma unroll
            for (int ct = 0; ct < 4; ct++)
#pragma unroll
                for (int r = 0; r < 4; r++) {
                    int node = n0 + rbase + rt * 16 + q * 4 + r;
                    if (node < N_NODES) {
                        int f = cbase + ct * 16 + mr;
                        Bm[(size_t)node * HID + f] = f2bf(acc[rt][ct][r]);
                    }
                }
    }
}

// ---------------- CSR gather + fused BN partial stats ----------------
// One wave per node, split into four 16-lane groups; each group fetches a
// DIFFERENT edge's full 256B row via uint4/lane. 4 rows per wave instruction,
// unroll x2 -> 8 rows in flight. Combine groups with shfl_xor(16|32).

__global__ __launch_bounds__(256) void k_gather(const uint4* __restrict__ Bm4,
                                                const int* __restrict__ rp,
                                                const int2* __restrict__ cw,
                                                const float* __restrict__ dinv,
                                                const float* __restrict__ bg,
                                                unsigned short* __restrict__ Aout,
                                                float* __restrict__ psum,
                                                float* __restrict__ psq) {
    __shared__ float ls[4 * HID], lq[4 * HID];
    int wave = threadIdx.x >> 6;
    int lane = threadIdx.x & 63;
    int s = lane & 15;   // 16B feature chunk: features s*8 .. s*8+7
    int p = lane >> 4;   // edge slot 0..3
    int v = blockIdx.x * 4 + wave;
    int beg = rp[v], end = rp[v + 1];
    float dv = dinv[v];
    float a0 = 0.f, a1 = 0.f, a2 = 0.f, a3 = 0.f, a4 = 0.f, a5 = 0.f, a6 = 0.f, a7 = 0.f;
    if (p == 0) {  // self-loop term
        uint4 u = Bm4[(size_t)v * 16 + s];
        float2 q0 = bfpair(u.x), q1 = bfpair(u.y), q2 = bfpair(u.z), q3 = bfpair(u.w);
        a0 = q0.x * dv; a1 = q0.y * dv; a2 = q1.x * dv; a3 = q1.y * dv;
        a4 = q2.x * dv; a5 = q2.y * dv; a6 = q3.x * dv; a7 = q3.y * dv;
    }
    int e = beg + p;
    for (; e + 4 < end; e += 8) {
        int2 pe0 = cw[e];
        int2 pe1 = cw[e + 4];
        uint4 u0 = Bm4[(size_t)pe0.x * 16 + s];
        uint4 u1 = Bm4[(size_t)pe1.x * 16 + s];
        float w0 = __int_as_float(pe0.y);
        float w1 = __int_as_float(pe1.y);
        float2 x0 = bfpair(u0.x), x1 = bfpair(u0.y), x2 = bfpair(u0.z), x3 = bfpair(u0.w);
        float2 y0 = bfpair(u1.x), y1 = bfpair(u1.y), y2 = bfpair(u1.z), y3 = bfpair(u1.w);
        a0 += x0.x * w0 + y0.x * w1;
        a1 += x0.y * w0 + y0.y * w1;
        a2 += x1.x * w0 + y1.x * w1;
        a3 += x1.y * w0 + y1.y * w1;
        a4 += x2.x * w0 + y2.x * w1;
        a5 += x2.y * w0 + y2.y * w1;
        a6 += x3.x * w0 + y3.x * w1;
        a7 += x3.y * w0 + y3.y * w1;
    }
    if (e < end) {
        int2 pe = cw[e];
        uint4 u = Bm4[(size_t)pe.x * 16 + s];
        float w = __int_as_float(pe.y);
        float2 x0 = bfpair(u.x), x1 = bfpair(u.y), x2 = bfpair(u.z), x3 = bfpair(u.w);
        a0 += x0.x * w; a1 += x0.y * w; a2 += x1.x * w; a3 += x1.y * w;
        a4 += x2.x * w; a5 += x2.y * w; a6 += x3.x * w; a7 += x3.y * w;
    }
    // combine the four 16-lane groups
    a0 += __shfl_xor(a0, 16); a1 += __shfl_xor(a1, 16);
    a2 += __shfl_xor(a2, 16); a3 += __shfl_xor(a3, 16);
    a4 += __shfl_xor(a4, 16); a5 += __shfl_xor(a5, 16);
    a6 += __shfl_xor(a6, 16); a7 += __shfl_xor(a7, 16);
    a0 += __shfl_xor(a0, 32); a1 += __shfl_xor(a1, 32);
    a2 += __shfl_xor(a2, 32); a3 += __shfl_xor(a3, 32);
    a4 += __shfl_xor(a4, 32); a5 += __shfl_xor(a5, 32);
    a6 += __shfl_xor(a6, 32); a7 += __shfl_xor(a7, 32);
    if (p == 0) {
        int f = s * 8;
        float r0 = a0 * dv + bg[f + 0];
        float r1 = a1 * dv + bg[f + 1];
        float r2 = a2 * dv + bg[f + 2];
        float r3 = a3 * dv + bg[f + 3];
        float r4 = a4 * dv + bg[f + 4];
        float r5 = a5 * dv + bg[f + 5];
        float r6 = a6 * dv + bg[f + 6];
        float r7 = a7 * dv + bg[f + 7];
        unsigned short b0 = f2bf(r0), b1 = f2bf(r1), b2 = f2bf(r2), b3 = f2bf(r3);
        unsigned short b4 = f2bf(r4), b5 = f2bf(r5), b6 = f2bf(r6), b7 = f2bf(r7);
        uint4 o;
        o.x = (unsigned)b0 | ((unsigned)b1 << 16);
        o.y = (unsigned)b2 | ((unsigned)b3 << 16);
        o.z = (unsigned)b4 | ((unsigned)b5 << 16);
        o.w = (unsigned)b6 | ((unsigned)b7 << 16);
        *(uint4*)&Aout[(size_t)v * HID + f] = o;
        // BN partial stats on the bf16-rounded values (what the next GEMM sees)
        float v0 = bf2f(b0), v1 = bf2f(b1), v2 = bf2f(b2), v3 = bf2f(b3);
        float v4 = bf2f(b4), v5 = bf2f(b5), v6 = bf2f(b6), v7 = bf2f(b7);
        float* lsw = &ls[wave * HID + f];
        float* lqw = &lq[wave * HID + f];
        lsw[0] = v0; lsw[1] = v1; lsw[2] = v2; lsw[3] = v3;
        lsw[4] = v4; lsw[5] = v5; lsw[6] = v6; lsw[7] = v7;
        lqw[0] = v0 * v0; lqw[1] = v1 * v1; lqw[2] = v2 * v2; lqw[3] = v3 * v3;
        lqw[4] = v4 * v4; lqw[5] = v5 * v5; lqw[6] = v6 * v6; lqw[7] = v7 * v7;
    }
    __syncthreads();
    int tt = threadIdx.x;
    if (tt < HID) {
        float ssum = ls[tt] + ls[HID + tt] + ls[2 * HID + tt] + ls[3 * HID + tt];
        float ssq = lq[tt] + lq[HID + tt] + lq[2 * HID + tt] + lq[3 * HID + tt];
        int slot = blockIdx.x & (BSLOT - 1);
        atomicAdd(&psum[slot * HID + tt], ssum);
        atomicAdd(&psq[slot * HID + tt], ssq);
    }
}

// ---------------- segmented pooling, chunked; derives layer-3 BN in-kernel ----------------

__global__ __launch_bounds__(128) void k_pool(const unsigned short* __restrict__ A,
                                              const float* __restrict__ psum,
                                              const float* __restrict__ psq,
                                              const float* __restrict__ gamma,
                                              const float* __restrict__ beta,
                                              const int* __restrict__ gstart,
                                              float* __restrict__ poolPart) {
    int g = blockIdx.x;
    int c = blockIdx.y;
    int f = threadIdx.x;
    float s = 0.f, s2 = 0.f;
#pragma unroll 8
    for (int b = 0; b < BSLOT; b++) {
        s += psum[b * HID + f];
        s2 += psq[b * HID + f];
    }
    const float invN = 1.f / (float)N_NODES;
    float mu = s * invN;
    float var = s2 * invN - mu * mu;
    float sc = rsqrtf(var + EPS) * gamma[f];
    float sh = beta[f] - mu * sc;
    int beg = gstart[g], end = gstart[g + 1];
    int len = end - beg;
    int per = (len + POOL_CHUNKS - 1) / POOL_CHUNKS;
    int s0 = beg + c * per;
    int s1 = min(s0 + per, end);
    float sa = 0.f, sb = 0.f, ma = 0.f, mb = 0.f;
    int n = s0;
    for (; n + 1 < s1; n += 2) {
        float v0 = bf2f(A[(size_t)n * HID + f]);
        float v1 = bf2f(A[(size_t)(n + 1) * HID + f]);
        v0 = fmaxf(v0 * sc + sh, 0.f);
        v1 = fmaxf(v1 * sc + sh, 0.f);
        sa += v0; ma = fmaxf(ma, v0);
        sb += v1; mb = fmaxf(mb, v1);
    }
    if (n < s1) {
        float v = fmaxf(bf2f(A[(size_t)n * HID + f]) * sc + sh, 0.f);
        sa += v; ma = fmaxf(ma, v);
    }
    poolPart[((size_t)g * POOL_CHUNKS + c) * 256 + f] = sa + sb;
    poolPart[((size_t)g * POOL_CHUNKS + c) * 256 + 128 + f] = fmaxf(ma, mb);
}

// ---------------- MLP head ----------------

__global__ __launch_bounds__(128) void k_head(const float* __restrict__ poolPart,
                                              const int* __restrict__ gstart,
                                              const float* __restrict__ W1, const float* __restrict__ b1,
                                              const float* __restrict__ W2, const float* __restrict__ b2,
                                              const float* __restrict__ W3, const float* __restrict__ b3,
                                              float* __restrict__ out) {
    __shared__ float pl[2 * HID];
    __shared__ float h1[HID];
    __shared__ float h2[HID / 2];
    int g = blockIdx.x, t = threadIdx.x;
    float cnt = fmaxf((float)(gstart[g + 1] - gstart[g]), 1.f);
    float s = 0.f, mx = 0.f;
#pragma unroll
    for (int c = 0; c < POOL_CHUNKS; c++) {
        const float* p = &poolPart[((size_t)g * POOL_CHUNKS + c) * 256];
        s += p[t];
        mx = fmaxf(mx, p[128 + t]);
    }
    pl[t] = s / cnt;
    pl[HID + t] = mx;
    __syncthreads();
    float acc = b1[t];
    for (int k = 0; k < 2 * HID; k++) acc += pl[k] * W1[k * HID + t];
    h1[t] = fmaxf(acc, 0.f);
    __syncthreads();
    if (t < HID / 2) {
        float a2 = b2[t];
        for (int k = 0; k < HID; k++) a2 += h1[k] * W2[k * (HID / 2) + t];
        h2[t] = fmaxf(a2, 0.f);
    }
    __syncthreads();
    if (t < NCLS) {
        float a3 = b3[t];
        for (int k = 0; k < HID / 2; k++) a3 += h2[k] * W3[k * NCLS + t];
        out[g * NCLS + t] = a3;
    }
}

extern "C" void kernel_launch(void* const* d_in, const int* in_sizes, int n_in,
                              void* d_out, int out_size, void* d_ws, size_t ws_size,
                              hipStream_t stream) {
    const float* x     = (const float*)d_in[0];
    const int*   ei    = (const int*)d_in[1];
    const int*   batch = (const int*)d_in[2];
    const float* Wp    = (const float*)d_in[3];
    const float* bp    = (const float*)d_in[4];
    const float* Wg    = (const float*)d_in[5];
    const float* bg    = (const float*)d_in[6];
    const float* gamma = (const float*)d_in[7];
    const float* beta  = (const float*)d_in[8];
    const float* W1    = (const float*)d_in[9];
    const float* b1    = (const float*)d_in[10];
    const float* W2    = (const float*)d_in[11];
    const float* b2    = (const float*)d_in[12];
    const float* W3    = (const float*)d_in[13];
    const float* b3    = (const float*)d_in[14];
    const int* src = ei;
    const int* dst = ei + N_EDGES;
    float* out = (float*)d_out;

    char* base = (char*)d_ws;
    size_t off = 0;
    auto alloc = [&](size_t bytes) -> void* {
        void* p = base + off;
        off += (bytes + 255) & ~(size_t)255;
        return p;
    };
    // zeroed region (one memset)
    int*   counts = (int*)alloc((size_t)N_NODES * 4);
    int*   cursor = (int*)alloc((size_t)N_NODES * 4);
    float* psum   = (float*)alloc((size_t)NLAYERS * BSLOT * HID * 4);
    float* psq    = (float*)alloc((size_t)NLAYERS * BSLOT * HID * 4);
    size_t zeroBytes = off;
    // non-zeroed scratch
    int*   rp      = (int*)alloc((size_t)(N_NODES + 1) * 4);
    int*   bsum    = (int*)alloc(128 * 4);
    int2*  cw      = (int2*)alloc((size_t)N_EDGES * 8);
    float* dinv    = (float*)alloc((size_t)N_NODES * 4);
    int*   gstart  = (int*)alloc((size_t)(N_GRAPHS + 1) * 4);
    float* poolPart= (float*)alloc((size_t)N_GRAPHS * POOL_CHUNKS * 256 * 4);
    unsigned short* A = (unsigned short*)alloc((size_t)N_NODES * HID * 2);
    unsigned short* B = (unsigned short*)alloc((size_t)N_NODES * HID * 2);
    (void)ws_size; (void)in_sizes; (void)n_in; (void)out_size;

    hipMemsetAsync(d_ws, 0, zeroBytes, stream);

    k_count<<<(N_EDGES + 255) / 256, 256, 0, stream>>>(dst, counts);
    k_scan1<<<SCAN_BLK, 512, 0, stream>>>(counts, rp, bsum);
    k_scan2g<<<2, 128, 0, stream>>>(bsum, batch, gstart);
    k_scan3d<<<SCAN_BLK, 512, 0, stream>>>(rp, bsum, counts, dinv);
    k_fill<<<(N_EDGES + 255) / 256, 256, 0, stream>>>(src, dst, rp, cursor, cw, dinv);

    for (int i = 0; i < NLAYERS; i++) {
        int pl = (i == 0) ? 0 : (i - 1);
        k_gemmM<<<768, 256, 0, stream>>>(A, x, Wp, bp, Wg + (size_t)i * HID * HID, B,
                                         psum + (size_t)pl * BSLOT * HID,
                                         psq + (size_t)pl * BSLOT * HID,
                                         gamma + pl * HID, beta + pl * HID,
                                         (i == 0) ? 1 : 0);
        k_gather<<<N_NODES / 4, 256, 0, stream>>>((const uint4*)B, rp, cw, dinv,
                                                  bg + i * HID, A,
                                                  psum + (size_t)i * BSLOT * HID,
                                                  psq + (size_t)i * BSLOT * HID);
    }
    dim3 pg(N_GRAPHS, POOL_CHUNKS);
    k_pool<<<pg, 128, 0, stream>>>(A, psum + (size_t)3 * BSLOT * HID,
                                   psq + (size_t)3 * BSLOT * HID,
                                   gamma + 3 * HID, beta + 3 * HID, gstart, poolPart);
    k_head<<<N_GRAPHS, 128, 0, stream>>>(poolPart, gstart, W1, b1, W2, b2, W3, b3, out);
}

// Round 9
// 392.261 us; speedup vs baseline: 2.9376x; 1.0482x over previous
//
#include <hip/hip_runtime.h>
#include <hip/hip_bf16.h>

#define N_NODES 50000
#define N_EDGES 600000
#define N_GRAPHS 64
#define HID 128
#define NLAYERS 4
#define IN_DIM 5
#define NCLS 5
#define EPS 1e-5f
#define SCAN_BLK ((N_NODES + 511) / 512)
#define POOL_CHUNKS 16
#define BSLOT 64  // BN-stat atomic slots (per layer)
#define WS 136    // bf16 LDS row stride (MFMA kernel)

typedef __attribute__((ext_vector_type(8))) short s16x8;
typedef __attribute__((ext_vector_type(4))) float f32x4;

// bf16 helpers (RNE)
__device__ __forceinline__ unsigned short f2bf(float x) {
    unsigned u = __float_as_uint(x);
    unsigned r = (u + 0x7fffu + ((u >> 16) & 1u)) >> 16;
    return (unsigned short)r;
}
__device__ __forceinline__ float2 bfpair(unsigned u) {
    float2 r;
    r.x = __uint_as_float(u << 16);
    r.y = __uint_as_float(u & 0xffff0000u);
    return r;
}
__device__ __forceinline__ float bf2f(unsigned short s) {
    return __uint_as_float(((unsigned)s) << 16);
}

// ---------------- CSR build ----------------

__global__ void k_count(const int* __restrict__ dst, int* __restrict__ cnt) {
    int i = blockIdx.x * blockDim.x + threadIdx.x;
    if (i < N_EDGES) atomicAdd(&cnt[dst[i]], 1);
}

__global__ void k_scan1(const int* __restrict__ cnt, int* __restrict__ rp, int* __restrict__ bsum) {
    __shared__ int s[512];
    int t = threadIdx.x;
    int i = blockIdx.x * 512 + t;
    int v = (i < N_NODES) ? cnt[i] : 0;
    s[t] = v;
    __syncthreads();
    for (int off = 1; off < 512; off <<= 1) {
        int x = (t >= off) ? s[t - off] : 0;
        __syncthreads();
        s[t] += x;
        __syncthreads();
    }
    if (i < N_NODES) rp[i + 1] = s[t];
    if (t == 511) bsum[blockIdx.x] = s[511];
}

__global__ void k_scan2g(int* __restrict__ bsum, const int* __restrict__ batch,
                         int* __restrict__ gstart) {
    if (blockIdx.x == 0) {
        __shared__ int s[128];
        int t = threadIdx.x;
        int v = (t < SCAN_BLK) ? bsum[t] : 0;
        s[t] = v;
        __syncthreads();
        for (int off = 1; off < 128; off <<= 1) {
            int x = (t >= off) ? s[t - off] : 0;
            __syncthreads();
            s[t] += x;
            __syncthreads();
        }
        if (t < SCAN_BLK) bsum[t] = s[t] - v;
    } else {
        int t = threadIdx.x;
        if (t <= N_GRAPHS) {
            int lo = 0, hi = N_NODES;
            while (lo < hi) {
                int mid = (lo + hi) >> 1;
                if (batch[mid] < t) lo = mid + 1; else hi = mid;
            }
            gstart[t] = lo;
        }
    }
}

__global__ void k_scan3d(int* __restrict__ rp, const int* __restrict__ bsum,
                         const int* __restrict__ cnt, float* __restrict__ dinv) {
    int i = blockIdx.x * 512 + threadIdx.x;
    if (i < N_NODES) {
        rp[i + 1] += bsum[blockIdx.x];
        dinv[i] = rsqrtf((float)(cnt[i] + 1));
    }
    if (i == 0) rp[0] = 0;
}

__global__ void k_fill(const int* __restrict__ src, const int* __restrict__ dst,
                       const int* __restrict__ rp, int* __restrict__ cursor,
                       int2* __restrict__ cw, const float* __restrict__ dinv) {
    int e = blockIdx.x * blockDim.x + threadIdx.x;
    if (e < N_EDGES) {
        int d = dst[e];
        int pos = atomicAdd(&cursor[d], 1);
        int s = src[e];
        int2 p;
        p.x = s;
        p.y = __float_as_int(dinv[s]);
        cw[rp[d] + pos] = p;
    }
}

// ---------------- W pre-transpose+convert: WtG[l][n][k] = bf16(W[l][k][n]) ----------------

__global__ void k_wconv(const float* __restrict__ Wg, unsigned short* __restrict__ WtG) {
    int idx = blockIdx.x * 256 + threadIdx.x;
    if (idx < NLAYERS * HID * HID) {
        int l = idx >> 14;
        int r = idx & 16383;
        int n = r >> 7, k = r & 127;
        WtG[idx] = f2bf(Wg[l * HID * HID + k * HID + n]);
    }
}

// ---------------- GEMM (MFMA): Bm(bf16) = act(in) @ W ----------------
// layer0: in = x @ Wp + bp (computed per tile). Else: in = relu(A*sc+sh),
// sc/sh derived in-kernel from the previous gather's psum/psq slots.
// W comes pre-transposed+bf16 (WtG[n][k]) -> coalesced uint4 + ds_write_b128.

__global__ __launch_bounds__(256) void k_gemmM(const unsigned short* __restrict__ Abf,
                                               const float* __restrict__ x,
                                               const float* __restrict__ Wp,
                                               const float* __restrict__ bp,
                                               const unsigned short* __restrict__ WtG,
                                               unsigned short* __restrict__ Bm,
                                               const float* __restrict__ psum,
                                               const float* __restrict__ psq,
                                               const float* __restrict__ gamma,
                                               const float* __restrict__ beta,
                                               int layer0) {
    __shared__ unsigned short Wt[HID * WS];
    __shared__ unsigned short Al[64 * WS];
    __shared__ float scl[HID], shf[HID];
    __shared__ float Wpl[IN_DIM * HID];
    __shared__ float bpl[HID];
    __shared__ float xl[64 * IN_DIM];
    int t = threadIdx.x;
    {
        const uint4* Wg4 = (const uint4*)WtG;
        for (int idx = t; idx < HID * 16; idx += 256) {
            int n = idx >> 4, c = idx & 15;
            *(uint4*)&Wt[n * WS + c * 8] = Wg4[idx];
        }
    }
    if (layer0) {
        for (int idx = t; idx < IN_DIM * HID; idx += 256) Wpl[idx] = Wp[idx];
        if (t < HID) bpl[t] = bp[t];
    } else if (t < HID) {
        float s = 0.f, s2 = 0.f;
#pragma unroll 8
        for (int b = 0; b < BSLOT; b++) {
            s += psum[b * HID + t];
            s2 += psq[b * HID + t];
        }
        const float invN = 1.f / (float)N_NODES;
        float mu = s * invN;
        float var = s2 * invN - mu * mu;
        float rs = rsqrtf(var + EPS) * gamma[t];
        scl[t] = rs;
        shf[t] = beta[t] - mu * rs;
    }
    int lane = t & 63, wv = t >> 6;
    int rbase = (wv & 1) * 32;
    int cbase = (wv >> 1) * 64;
    int mr = lane & 15, q = lane >> 4;
    const int numTiles = (N_NODES + 63) / 64;
    for (int tile = blockIdx.x; tile < numTiles; tile += gridDim.x) {
        int n0 = tile * 64;
        __syncthreads();  // orders scl/Wt writes (1st iter) + Al reuse safety
        if (layer0) {
            for (int idx = t; idx < 64 * IN_DIM; idx += 256) {
                int g = n0 * IN_DIM + idx;
                xl[idx] = (g < N_NODES * IN_DIM) ? x[g] : 0.f;
            }
            __syncthreads();
            for (int idx = t; idx < 64 * HID; idx += 256) {
                int n = idx >> 7, k = idx & 127;
                float acc = bpl[k];
#pragma unroll
                for (int j = 0; j < IN_DIM; j++) acc += xl[n * IN_DIM + j] * Wpl[j * HID + k];
                Al[n * WS + k] = f2bf(acc);
            }
        } else {
            const uint2* Ag = (const uint2*)(Abf + (size_t)n0 * HID);
            int limRow = min(64, N_NODES - n0);
            for (int idx = t; idx < 64 * 32; idx += 256) {
                int row = idx >> 5, c4 = idx & 31;
                uint2 u = (row < limRow) ? Ag[row * 32 + c4] : make_uint2(0u, 0u);
                float2 ab = bfpair(u.x);
                float2 cd = bfpair(u.y);
                int kf = c4 * 4;
                float4 sc = *(const float4*)&scl[kf];
                float4 sh = *(const float4*)&shf[kf];
                float v0 = fmaxf(ab.x * sc.x + sh.x, 0.f);
                float v1 = fmaxf(ab.y * sc.y + sh.y, 0.f);
                float v2 = fmaxf(cd.x * sc.z + sh.z, 0.f);
                float v3 = fmaxf(cd.y * sc.w + sh.w, 0.f);
                unsigned lo = (unsigned)f2bf(v0) | ((unsigned)f2bf(v1) << 16);
                unsigned hi = (unsigned)f2bf(v2) | ((unsigned)f2bf(v3) << 16);
                *(uint2*)&Al[row * WS + kf] = make_uint2(lo, hi);
            }
        }
        __syncthreads();
        f32x4 acc[2][4];
#pragma unroll
        for (int rt = 0; rt < 2; rt++)
#pragma unroll
            for (int ct = 0; ct < 4; ct++) acc[rt][ct] = (f32x4){0.f, 0.f, 0.f, 0.f};
#pragma unroll
        for (int kk = 0; kk < HID; kk += 32) {
            s16x8 a0 = *(const s16x8*)&Al[(rbase + mr) * WS + kk + q * 8];
            s16x8 a1 = *(const s16x8*)&Al[(rbase + 16 + mr) * WS + kk + q * 8];
#pragma unroll
            for (int ct = 0; ct < 4; ct++) {
                s16x8 b = *(const s16x8*)&Wt[(cbase + ct * 16 + mr) * WS + kk + q * 8];
                acc[0][ct] = __builtin_amdgcn_mfma_f32_16x16x32_bf16(a0, b, acc[0][ct], 0, 0, 0);
                acc[1][ct] = __builtin_amdgcn_mfma_f32_16x16x32_bf16(a1, b, acc[1][ct], 0, 0, 0);
            }
        }
#pragma unroll
        for (int rt = 0; rt < 2; rt++)
#pragma unroll
            for (int ct = 0; ct < 4; ct++)
#pragma unroll
                for (int r = 0; r < 4; r++) {
                    int node = n0 + rbase + rt * 16 + q * 4 + r;
                    if (node < N_NODES) {
                        int f = cbase + ct * 16 + mr;
                        Bm[(size_t)node * HID + f] = f2bf(acc[rt][ct][r]);
                    }
                }
    }
}

// ---------------- CSR gather + fused BN partial stats ----------------
// 16 nodes per block: 4 waves x 4 serial nodes. Within a node, four 16-lane
// groups each fetch a DIFFERENT edge's 256B row (uint4/lane), unroll x2 ->
// 8 rows in flight. BN stats accumulate in registers across the 4 nodes;
// one LDS reduce + 256-atomic tail per block (4x fewer atomics than 4-node blocks).

__global__ __launch_bounds__(256) void k_gather(const uint4* __restrict__ Bm4,
                                                const int* __restrict__ rp,
                                                const int2* __restrict__ cw,
                                                const float* __restrict__ dinv,
                                                const float* __restrict__ bg,
                                                unsigned short* __restrict__ Aout,
                                                float* __restrict__ psum,
                                                float* __restrict__ psq) {
    __shared__ float ls[4 * HID], lq[4 * HID];
    int wave = threadIdx.x >> 6;
    int lane = threadIdx.x & 63;
    int s = lane & 15;   // 16B feature chunk: features s*8 .. s*8+7
    int p = lane >> 4;   // edge slot 0..3
    int f = s * 8;
    float ts0 = 0.f, ts1 = 0.f, ts2 = 0.f, ts3 = 0.f, ts4 = 0.f, ts5 = 0.f, ts6 = 0.f, ts7 = 0.f;
    float tq0 = 0.f, tq1 = 0.f, tq2 = 0.f, tq3 = 0.f, tq4 = 0.f, tq5 = 0.f, tq6 = 0.f, tq7 = 0.f;
#pragma unroll 1
    for (int it = 0; it < 4; it++) {
        int v = blockIdx.x * 16 + wave * 4 + it;
        int beg = rp[v], end = rp[v + 1];
        float dv = dinv[v];
        float a0 = 0.f, a1 = 0.f, a2 = 0.f, a3 = 0.f, a4 = 0.f, a5 = 0.f, a6 = 0.f, a7 = 0.f;
        if (p == 0) {  // self-loop term
            uint4 u = Bm4[(size_t)v * 16 + s];
            float2 q0 = bfpair(u.x), q1 = bfpair(u.y), q2 = bfpair(u.z), q3 = bfpair(u.w);
            a0 = q0.x * dv; a1 = q0.y * dv; a2 = q1.x * dv; a3 = q1.y * dv;
            a4 = q2.x * dv; a5 = q2.y * dv; a6 = q3.x * dv; a7 = q3.y * dv;
        }
        int e = beg + p;
        for (; e + 4 < end; e += 8) {
            int2 pe0 = cw[e];
            int2 pe1 = cw[e + 4];
            uint4 u0 = Bm4[(size_t)pe0.x * 16 + s];
            uint4 u1 = Bm4[(size_t)pe1.x * 16 + s];
            float w0 = __int_as_float(pe0.y);
            float w1 = __int_as_float(pe1.y);
            float2 x0 = bfpair(u0.x), x1 = bfpair(u0.y), x2 = bfpair(u0.z), x3 = bfpair(u0.w);
            float2 y0 = bfpair(u1.x), y1 = bfpair(u1.y), y2 = bfpair(u1.z), y3 = bfpair(u1.w);
            a0 += x0.x * w0 + y0.x * w1;
            a1 += x0.y * w0 + y0.y * w1;
            a2 += x1.x * w0 + y1.x * w1;
            a3 += x1.y * w0 + y1.y * w1;
            a4 += x2.x * w0 + y2.x * w1;
            a5 += x2.y * w0 + y2.y * w1;
            a6 += x3.x * w0 + y3.x * w1;
            a7 += x3.y * w0 + y3.y * w1;
        }
        if (e < end) {
            int2 pe = cw[e];
            uint4 u = Bm4[(size_t)pe.x * 16 + s];
            float w = __int_as_float(pe.y);
            float2 x0 = bfpair(u.x), x1 = bfpair(u.y), x2 = bfpair(u.z), x3 = bfpair(u.w);
            a0 += x0.x * w; a1 += x0.y * w; a2 += x1.x * w; a3 += x1.y * w;
            a4 += x2.x * w; a5 += x2.y * w; a6 += x3.x * w; a7 += x3.y * w;
        }
        // combine the four 16-lane groups
        a0 += __shfl_xor(a0, 16); a1 += __shfl_xor(a1, 16);
        a2 += __shfl_xor(a2, 16); a3 += __shfl_xor(a3, 16);
        a4 += __shfl_xor(a4, 16); a5 += __shfl_xor(a5, 16);
        a6 += __shfl_xor(a6, 16); a7 += __shfl_xor(a7, 16);
        a0 += __shfl_xor(a0, 32); a1 += __shfl_xor(a1, 32);
        a2 += __shfl_xor(a2, 32); a3 += __shfl_xor(a3, 32);
        a4 += __shfl_xor(a4, 32); a5 += __shfl_xor(a5, 32);
        a6 += __shfl_xor(a6, 32); a7 += __shfl_xor(a7, 32);
        if (p == 0) {
            float r0 = a0 * dv + bg[f + 0];
            float r1 = a1 * dv + bg[f + 1];
            float r2 = a2 * dv + bg[f + 2];
            float r3 = a3 * dv + bg[f + 3];
            float r4 = a4 * dv + bg[f + 4];
            float r5 = a5 * dv + bg[f + 5];
            float r6 = a6 * dv + bg[f + 6];
            float r7 = a7 * dv + bg[f + 7];
            unsigned short b0 = f2bf(r0), b1 = f2bf(r1), b2 = f2bf(r2), b3 = f2bf(r3);
            unsigned short b4 = f2bf(r4), b5 = f2bf(r5), b6 = f2bf(r6), b7 = f2bf(r7);
            uint4 o;
            o.x = (unsigned)b0 | ((unsigned)b1 << 16);
            o.y = (unsigned)b2 | ((unsigned)b3 << 16);
            o.z = (unsigned)b4 | ((unsigned)b5 << 16);
            o.w = (unsigned)b6 | ((unsigned)b7 << 16);
            *(uint4*)&Aout[(size_t)v * HID + f] = o;
            // BN stats on the bf16-rounded values (what the next GEMM sees)
            float v0 = bf2f(b0), v1 = bf2f(b1), v2 = bf2f(b2), v3 = bf2f(b3);
            float v4 = bf2f(b4), v5 = bf2f(b5), v6 = bf2f(b6), v7 = bf2f(b7);
            ts0 += v0; ts1 += v1; ts2 += v2; ts3 += v3;
            ts4 += v4; ts5 += v5; ts6 += v6; ts7 += v7;
            tq0 += v0 * v0; tq1 += v1 * v1; tq2 += v2 * v2; tq3 += v3 * v3;
            tq4 += v4 * v4; tq5 += v5 * v5; tq6 += v6 * v6; tq7 += v7 * v7;
        }
    }
    if (p == 0) {
        float* lsw = &ls[wave * HID + f];
        float* lqw = &lq[wave * HID + f];
        lsw[0] = ts0; lsw[1] = ts1; lsw[2] = ts2; lsw[3] = ts3;
        lsw[4] = ts4; lsw[5] = ts5; lsw[6] = ts6; lsw[7] = ts7;
        lqw[0] = tq0; lqw[1] = tq1; lqw[2] = tq2; lqw[3] = tq3;
        lqw[4] = tq4; lqw[5] = tq5; lqw[6] = tq6; lqw[7] = tq7;
    }
    __syncthreads();
    int tt = threadIdx.x;
    if (tt < HID) {
        float ssum = ls[tt] + ls[HID + tt] + ls[2 * HID + tt] + ls[3 * HID + tt];
        float ssq = lq[tt] + lq[HID + tt] + lq[2 * HID + tt] + lq[3 * HID + tt];
        int slot = blockIdx.x & (BSLOT - 1);
        atomicAdd(&psum[slot * HID + tt], ssum);
        atomicAdd(&psq[slot * HID + tt], ssq);
    }
}

// ---------------- segmented pooling, chunked; derives layer-3 BN in-kernel ----------------

__global__ __launch_bounds__(128) void k_pool(const unsigned short* __restrict__ A,
                                              const float* __restrict__ psum,
                                              const float* __restrict__ psq,
                                              const float* __restrict__ gamma,
                                              const float* __restrict__ beta,
                                              const int* __restrict__ gstart,
                                              float* __restrict__ poolPart) {
    int g = blockIdx.x;
    int c = blockIdx.y;
    int f = threadIdx.x;
    float s = 0.f, s2 = 0.f;
#pragma unroll 8
    for (int b = 0; b < BSLOT; b++) {
        s += psum[b * HID + f];
        s2 += psq[b * HID + f];
    }
    const float invN = 1.f / (float)N_NODES;
    float mu = s * invN;
    float var = s2 * invN - mu * mu;
    float sc = rsqrtf(var + EPS) * gamma[f];
    float sh = beta[f] - mu * sc;
    int beg = gstart[g], end = gstart[g + 1];
    int len = end - beg;
    int per = (len + POOL_CHUNKS - 1) / POOL_CHUNKS;
    int s0 = beg + c * per;
    int s1 = min(s0 + per, end);
    float sa = 0.f, sb = 0.f, ma = 0.f, mb = 0.f;
    int n = s0;
    for (; n + 1 < s1; n += 2) {
        float v0 = bf2f(A[(size_t)n * HID + f]);
        float v1 = bf2f(A[(size_t)(n + 1) * HID + f]);
        v0 = fmaxf(v0 * sc + sh, 0.f);
        v1 = fmaxf(v1 * sc + sh, 0.f);
        sa += v0; ma = fmaxf(ma, v0);
        sb += v1; mb = fmaxf(mb, v1);
    }
    if (n < s1) {
        float v = fmaxf(bf2f(A[(size_t)n * HID + f]) * sc + sh, 0.f);
        sa += v; ma = fmaxf(ma, v);
    }
    poolPart[((size_t)g * POOL_CHUNKS + c) * 256 + f] = sa + sb;
    poolPart[((size_t)g * POOL_CHUNKS + c) * 256 + 128 + f] = fmaxf(ma, mb);
}

// ---------------- MLP head ----------------

__global__ __launch_bounds__(128) void k_head(const float* __restrict__ poolPart,
                                              const int* __restrict__ gstart,
                                              const float* __restrict__ W1, const float* __restrict__ b1,
                                              const float* __restrict__ W2, const float* __restrict__ b2,
                                              const float* __restrict__ W3, const float* __restrict__ b3,
                                              float* __restrict__ out) {
    __shared__ float pl[2 * HID];
    __shared__ float h1[HID];
    __shared__ float h2[HID / 2];
    int g = blockIdx.x, t = threadIdx.x;
    float cnt = fmaxf((float)(gstart[g + 1] - gstart[g]), 1.f);
    float s = 0.f, mx = 0.f;
#pragma unroll
    for (int c = 0; c < POOL_CHUNKS; c++) {
        const float* p = &poolPart[((size_t)g * POOL_CHUNKS + c) * 256];
        s += p[t];
        mx = fmaxf(mx, p[128 + t]);
    }
    pl[t] = s / cnt;
    pl[HID + t] = mx;
    __syncthreads();
    float acc = b1[t];
    for (int k = 0; k < 2 * HID; k++) acc += pl[k] * W1[k * HID + t];
    h1[t] = fmaxf(acc, 0.f);
    __syncthreads();
    if (t < HID / 2) {
        float a2 = b2[t];
        for (int k = 0; k < HID; k++) a2 += h1[k] * W2[k * (HID / 2) + t];
        h2[t] = fmaxf(a2, 0.f);
    }
    __syncthreads();
    if (t < NCLS) {
        float a3 = b3[t];
        for (int k = 0; k < HID / 2; k++) a3 += h2[k] * W3[k * NCLS + t];
        out[g * NCLS + t] = a3;
    }
}

extern "C" void kernel_launch(void* const* d_in, const int* in_sizes, int n_in,
                              void* d_out, int out_size, void* d_ws, size_t ws_size,
                              hipStream_t stream) {
    const float* x     = (const float*)d_in[0];
    const int*   ei    = (const int*)d_in[1];
    const int*   batch = (const int*)d_in[2];
    const float* Wp    = (const float*)d_in[3];
    const float* bp    = (const float*)d_in[4];
    const float* Wg    = (const float*)d_in[5];
    const float* bg    = (const float*)d_in[6];
    const float* gamma = (const float*)d_in[7];
    const float* beta  = (const float*)d_in[8];
    const float* W1    = (const float*)d_in[9];
    const float* b1    = (const float*)d_in[10];
    const float* W2    = (const float*)d_in[11];
    const float* b2    = (const float*)d_in[12];
    const float* W3    = (const float*)d_in[13];
    const float* b3    = (const float*)d_in[14];
    const int* src = ei;
    const int* dst = ei + N_EDGES;
    float* out = (float*)d_out;

    char* base = (char*)d_ws;
    size_t off = 0;
    auto alloc = [&](size_t bytes) -> void* {
        void* p = base + off;
        off += (bytes + 255) & ~(size_t)255;
        return p;
    };
    // zeroed region (one memset)
    int*   counts = (int*)alloc((size_t)N_NODES * 4);
    int*   cursor = (int*)alloc((size_t)N_NODES * 4);
    float* psum   = (float*)alloc((size_t)NLAYERS * BSLOT * HID * 4);
    float* psq    = (float*)alloc((size_t)NLAYERS * BSLOT * HID * 4);
    size_t zeroBytes = off;
    // non-zeroed scratch
    int*   rp      = (int*)alloc((size_t)(N_NODES + 1) * 4);
    int*   bsum    = (int*)alloc(128 * 4);
    int2*  cw      = (int2*)alloc((size_t)N_EDGES * 8);
    float* dinv    = (float*)alloc((size_t)N_NODES * 4);
    int*   gstart  = (int*)alloc((size_t)(N_GRAPHS + 1) * 4);
    float* poolPart= (float*)alloc((size_t)N_GRAPHS * POOL_CHUNKS * 256 * 4);
    unsigned short* WtG = (unsigned short*)alloc((size_t)NLAYERS * HID * HID * 2);
    unsigned short* A = (unsigned short*)alloc((size_t)N_NODES * HID * 2);
    unsigned short* B = (unsigned short*)alloc((size_t)N_NODES * HID * 2);
    (void)ws_size; (void)in_sizes; (void)n_in; (void)out_size;

    hipMemsetAsync(d_ws, 0, zeroBytes, stream);

    k_count<<<(N_EDGES + 255) / 256, 256, 0, stream>>>(dst, counts);
    k_scan1<<<SCAN_BLK, 512, 0, stream>>>(counts, rp, bsum);
    k_scan2g<<<2, 128, 0, stream>>>(bsum, batch, gstart);
    k_scan3d<<<SCAN_BLK, 512, 0, stream>>>(rp, bsum, counts, dinv);
    k_fill<<<(N_EDGES + 255) / 256, 256, 0, stream>>>(src, dst, rp, cursor, cw, dinv);
    k_wconv<<<(NLAYERS * HID * HID + 255) / 256, 256, 0, stream>>>(Wg, WtG);

    for (int i = 0; i < NLAYERS; i++) {
        int pl = (i == 0) ? 0 : (i - 1);
        k_gemmM<<<768, 256, 0, stream>>>(A, x, Wp, bp, WtG + (size_t)i * HID * HID, B,
                                         psum + (size_t)pl * BSLOT * HID,
                                         psq + (size_t)pl * BSLOT * HID,
                                         gamma + pl * HID, beta + pl * HID,
                                         (i == 0) ? 1 : 0);
        k_gather<<<N_NODES / 16, 256, 0, stream>>>((const uint4*)B, rp, cw, dinv,
                                                   bg + i * HID, A,
                                                   psum + (size_t)i * BSLOT * HID,
                                                   psq + (size_t)i * BSLOT * HID);
    }
    dim3 pg(N_GRAPHS, POOL_CHUNKS);
    k_pool<<<pg, 128, 0, stream>>>(A, psum + (size_t)3 * BSLOT * HID,
                                   psq + (size_t)3 * BSLOT * HID,
                                   gamma + 3 * HID, beta + 3 * HID, gstart, poolPart);
    k_head<<<N_GRAPHS, 128, 0, stream>>>(poolPart, gstart, W1, b1, W2, b2, W3, b3, out);
}